// Round 7
// baseline (702.866 us; speedup 1.0000x reference)
//
#include <hip/hip_runtime.h>
#include <hip/hip_bf16.h>

#define N_NODES 50000
#define E_EDGES 800000
#define IN_F 128
#define HIDF 64
#define HEADS 4
#define OUT_F 40
#define GROUPS 8
#define D_F 256
#define NEG 0.2f
#define LNEPS 1e-5f
#define POOL_CHUNK 128
#define POOL_BLOCKS ((N_NODES + POOL_CHUNK - 1) / POOL_CHUNK)   // 391
#define NB256 ((N_NODES + 255) / 256)                            // 196

// canonical bf16 parameter buffer: element offsets
#define OFF_X    0
#define OFF_EW1  6400000
#define OFF_EB1  6408192
#define OFF_EG   6408256
#define OFF_EBE  6408320
#define OFF_EW2  6408384
#define OFF_EB2  6412480
#define OFF_C0W  6412544
#define OFF_C0AS 6428928
#define OFF_C0AD 6429184
#define OFF_C0B  6429440
#define OFF_C1W  6429696
#define OFF_C1AS 6495232
#define OFF_C1AD 6495488
#define OFF_C1B  6495744
#define OFF_C2W  6496000
#define OFF_C2AS 6561536
#define OFF_C2AD 6561792
#define OFF_C2B  6562048
#define OFF_DW1  6562304
#define OFF_DB1  6578688
#define OFF_DG   6578752
#define OFF_DBE  6578816
#define OFF_DW2  6578880
#define OFF_DB2  6581440
#define CANON_TOT 6581480

__device__ __constant__ int c_off[26] = {
    OFF_X, OFF_EW1, OFF_EB1, OFF_EG, OFF_EBE, OFF_EW2, OFF_EB2,
    OFF_C0W, OFF_C0AS, OFF_C0AD, OFF_C0B,
    OFF_C1W, OFF_C1AS, OFF_C1AD, OFF_C1B,
    OFF_C2W, OFF_C2AS, OFF_C2AD, OFF_C2B,
    OFF_DW1, OFF_DB1, OFF_DG, OFF_DBE, OFF_DW2, OFF_DB2, CANON_TOT};

typedef __attribute__((ext_vector_type(8))) short bf16x8;
typedef __attribute__((ext_vector_type(4))) float f32x4;

__device__ __forceinline__ float bf2f(unsigned short u) {
    union { unsigned int i; float f; } v; v.i = ((unsigned int)u) << 16; return v.f;
}
__device__ __forceinline__ unsigned short f2bf(float f) {
    union { float f; unsigned int i; } v; v.f = f;
    unsigned int r = v.i + 0x7FFF + ((v.i >> 16) & 1);   // RNE
    return (unsigned short)(r >> 16);
}

// ---------- dtype flag ----------
__global__ void flag_k(const unsigned short* __restrict__ encg, int* __restrict__ flag) {
    if (threadIdx.x == 0 && blockIdx.x == 0) {
        unsigned short a = encg[0], b = encg[1];
        int f = 0;
        if (a == 0x0000 && b == 0x3F80) f = 1;
        *flag = f;
    }
}

// ---------- canonicalize ----------
struct SP { const void* q[25]; };
__global__ __launch_bounds__(256) void convert_k(SP sp, const int* __restrict__ flag,
                                                 unsigned short* __restrict__ canon) {
    int i = blockIdx.x * 256 + threadIdx.x;
    if (i >= CANON_TOT) return;
    int t = 0;
    while (i >= c_off[t + 1]) ++t;
    int j = i - c_off[t];
    const void* s = sp.q[t];
    unsigned short v;
    if (*flag == 0) v = ((const unsigned short*)s)[j];
    else            v = f2bf(((const float*)s)[j]);
    canon[i] = v;
}

// ---------- weight transposes ----------
__global__ void wt_k(const unsigned short* __restrict__ canon,
                     unsigned short* __restrict__ wt0, unsigned short* __restrict__ wt1,
                     unsigned short* __restrict__ wt2, unsigned short* __restrict__ w1t,
                     unsigned short* __restrict__ w2t) {
    int i = blockIdx.x * 256 + threadIdx.x;   // 65536 threads
    if (i < 8192) {
        int k = i >> 6, n = i & 63;
        w1t[n * 128 + k] = canon[OFF_EW1 + k * 64 + n];
    }
    if (i < 4096) {
        int k = i >> 6, n = i & 63;
        w2t[n * 64 + k] = canon[OFF_EW2 + k * 64 + n];
    }
    if (i < 16384) {
        int k = i >> 8, n = i & 255;
        wt0[n * 64 + k] = canon[OFF_C0W + i];
    }
    if (i < 65536) {
        int k = i >> 8, n = i & 255;
        wt1[n * 256 + k] = canon[OFF_C1W + i];
        wt2[n * 256 + k] = canon[OFF_C2W + i];
    }
}

// ---------------- encoder stage 1: T1 = relu(LN(x@w1+b1)), MFMA + fused LN ----------------
__global__ __launch_bounds__(128) void enc1_k(const unsigned short* __restrict__ canon,
                                              const unsigned short* __restrict__ w1t,
                                              unsigned short* __restrict__ T1) {
    const unsigned short* x = canon + OFF_X;
    __shared__ unsigned short As[128 * 72];
    __shared__ unsigned short Bs[64 * 72];
    int tid = threadIdx.x, wave = tid >> 6, lane = tid & 63;
    int q = lane >> 4, l = lane & 15;
    int row0 = blockIdx.x * 128;
    f32x4 acc[4][4];
#pragma unroll
    for (int a = 0; a < 4; ++a)
#pragma unroll
        for (int b = 0; b < 4; ++b) acc[a][b] = (f32x4){0.f, 0.f, 0.f, 0.f};
    for (int kb = 0; kb < IN_F; kb += 64) {
#pragma unroll
        for (int it = 0; it < 8; ++it) {
            int cid = it * 128 + tid;
            int r = cid >> 3, kc = cid & 7;
            int gr = row0 + r;
            uint4 v = make_uint4(0, 0, 0, 0);
            if (gr < N_NODES) v = *(const uint4*)(x + (size_t)gr * IN_F + kb + kc * 8);
            *(uint4*)&As[r * 72 + kc * 8] = v;
        }
#pragma unroll
        for (int it = 0; it < 4; ++it) {
            int cid = it * 128 + tid;
            int r = cid >> 3, kc = cid & 7;
            uint4 w = *(const uint4*)(w1t + (size_t)r * IN_F + kb + kc * 8);
            *(uint4*)&Bs[r * 72 + kc * 8] = w;
        }
        __syncthreads();
#pragma unroll
        for (int ks = 0; ks < 64; ks += 32) {
            bf16x8 af[4], bfr[4];
#pragma unroll
            for (int mt = 0; mt < 4; ++mt)
                af[mt] = *(const bf16x8*)&As[(wave * 64 + mt * 16 + l) * 72 + ks + q * 8];
#pragma unroll
            for (int nt = 0; nt < 4; ++nt)
                bfr[nt] = *(const bf16x8*)&Bs[(nt * 16 + l) * 72 + ks + q * 8];
#pragma unroll
            for (int mt = 0; mt < 4; ++mt)
#pragma unroll
                for (int nt = 0; nt < 4; ++nt)
                    acc[mt][nt] = __builtin_amdgcn_mfma_f32_16x16x32_bf16(
                        af[mt], bfr[nt], acc[mt][nt], 0, 0, 0);
        }
        __syncthreads();
    }
    float b1c[4], gc[4], bec[4];
#pragma unroll
    for (int nt = 0; nt < 4; ++nt) {
        int c = nt * 16 + l;
        b1c[nt] = bf2f(canon[OFF_EB1 + c]);
        gc[nt]  = bf2f(canon[OFF_EG + c]);
        bec[nt] = bf2f(canon[OFF_EBE + c]);
    }
#pragma unroll
    for (int mt = 0; mt < 4; ++mt) {
#pragma unroll
        for (int r = 0; r < 4; ++r) {
            int grow = row0 + wave * 64 + mt * 16 + q * 4 + r;
            float v0 = acc[mt][0][r] + b1c[0];
            float v1 = acc[mt][1][r] + b1c[1];
            float v2 = acc[mt][2][r] + b1c[2];
            float v3 = acc[mt][3][r] + b1c[3];
            float s = v0 + v1 + v2 + v3;
#pragma unroll
            for (int off = 1; off < 16; off <<= 1) s += __shfl_xor(s, off);
            float mean = s * (1.0f / 64.0f);
            float d0 = v0 - mean, d1 = v1 - mean, d2 = v2 - mean, d3 = v3 - mean;
            float vs = d0 * d0 + d1 * d1 + d2 * d2 + d3 * d3;
#pragma unroll
            for (int off = 1; off < 16; off <<= 1) vs += __shfl_xor(vs, off);
            float rstd = rsqrtf(vs * (1.0f / 64.0f) + LNEPS);
            if (grow < N_NODES) {
                unsigned short* trow = T1 + (size_t)grow * HIDF;
                float o0 = gc[0] * d0 * rstd + bec[0]; o0 = fmaxf(o0, 0.f);
                float o1 = gc[1] * d1 * rstd + bec[1]; o1 = fmaxf(o1, 0.f);
                float o2 = gc[2] * d2 * rstd + bec[2]; o2 = fmaxf(o2, 0.f);
                float o3 = gc[3] * d3 * rstd + bec[3]; o3 = fmaxf(o3, 0.f);
                trow[l] = f2bf(o0); trow[16 + l] = f2bf(o1);
                trow[32 + l] = f2bf(o2); trow[48 + l] = f2bf(o3);
            }
        }
    }
}

// ---------------- encoder stage 2: h0 = T1 @ w2 + b2 ----------------
__global__ __launch_bounds__(128) void enc2_k(const unsigned short* __restrict__ canon,
                                              const unsigned short* __restrict__ T1,
                                              const unsigned short* __restrict__ w2t,
                                              unsigned short* __restrict__ h0) {
    __shared__ unsigned short As[128 * 72];
    __shared__ unsigned short Bs[64 * 72];
    int tid = threadIdx.x, wave = tid >> 6, lane = tid & 63;
    int q = lane >> 4, l = lane & 15;
    int row0 = blockIdx.x * 128;
    f32x4 acc[4][4];
#pragma unroll
    for (int a = 0; a < 4; ++a)
#pragma unroll
        for (int b = 0; b < 4; ++b) acc[a][b] = (f32x4){0.f, 0.f, 0.f, 0.f};
#pragma unroll
    for (int it = 0; it < 8; ++it) {
        int cid = it * 128 + tid;
        int r = cid >> 3, kc = cid & 7;
        int gr = row0 + r;
        uint4 v = make_uint4(0, 0, 0, 0);
        if (gr < N_NODES) v = *(const uint4*)(T1 + (size_t)gr * HIDF + kc * 8);
        *(uint4*)&As[r * 72 + kc * 8] = v;
    }
#pragma unroll
    for (int it = 0; it < 4; ++it) {
        int cid = it * 128 + tid;
        int r = cid >> 3, kc = cid & 7;
        uint4 w = *(const uint4*)(w2t + (size_t)r * HIDF + kc * 8);
        *(uint4*)&Bs[r * 72 + kc * 8] = w;
    }
    __syncthreads();
#pragma unroll
    for (int ks = 0; ks < 64; ks += 32) {
        bf16x8 af[4], bfr[4];
#pragma unroll
        for (int mt = 0; mt < 4; ++mt)
            af[mt] = *(const bf16x8*)&As[(wave * 64 + mt * 16 + l) * 72 + ks + q * 8];
#pragma unroll
        for (int nt = 0; nt < 4; ++nt)
            bfr[nt] = *(const bf16x8*)&Bs[(nt * 16 + l) * 72 + ks + q * 8];
#pragma unroll
        for (int mt = 0; mt < 4; ++mt)
#pragma unroll
            for (int nt = 0; nt < 4; ++nt)
                acc[mt][nt] = __builtin_amdgcn_mfma_f32_16x16x32_bf16(
                    af[mt], bfr[nt], acc[mt][nt], 0, 0, 0);
    }
    float b2c[4];
#pragma unroll
    for (int nt = 0; nt < 4; ++nt) b2c[nt] = bf2f(canon[OFF_EB2 + nt * 16 + l]);
#pragma unroll
    for (int mt = 0; mt < 4; ++mt) {
#pragma unroll
        for (int r = 0; r < 4; ++r) {
            int grow = row0 + wave * 64 + mt * 16 + q * 4 + r;
            if (grow < N_NODES) {
                unsigned short* hrow = h0 + (size_t)grow * HIDF;
#pragma unroll
                for (int nt = 0; nt < 4; ++nt)
                    hrow[nt * 16 + l] = f2bf(acc[mt][nt][r] + b2c[nt]);
            }
        }
    }
}

// ---------------- CSR build ----------------
__global__ void deg_init_k(int* __restrict__ deg) {
    int i = blockIdx.x * 256 + threadIdx.x;
    if (i < N_NODES) deg[i] = 1;
}
__global__ void deg_count_k(const int* __restrict__ dstI, int* __restrict__ deg) {
    int i = blockIdx.x * 256 + threadIdx.x;
    if (i < E_EDGES) atomicAdd(&deg[dstI[i]], 1);
}
__global__ __launch_bounds__(256) void scan1_k(const int* __restrict__ deg, int* __restrict__ excl,
                                               int* __restrict__ bsums) {
    int tid = threadIdx.x, lane = tid & 63, wv = tid >> 6;
    int gid = blockIdx.x * 256 + tid;
    int v = (gid < N_NODES) ? deg[gid] : 0;
    int inc = v;
#pragma unroll
    for (int off = 1; off < 64; off <<= 1) { int t = __shfl_up(inc, off); if (lane >= off) inc += t; }
    __shared__ int wsum[4];
    if (lane == 63) wsum[wv] = inc;
    __syncthreads();
    int wo = 0;
    for (int w = 0; w < wv; ++w) wo += wsum[w];
    int incl = inc + wo;
    if (gid < N_NODES) excl[gid] = incl - v;
    if (tid == 255) bsums[blockIdx.x] = incl;
}
__global__ __launch_bounds__(256) void scan2_k(const int* __restrict__ bsums, int* __restrict__ boff,
                                               int* __restrict__ totalp) {
    int tid = threadIdx.x, lane = tid & 63, wv = tid >> 6;
    int v = (tid < NB256) ? bsums[tid] : 0;
    int inc = v;
#pragma unroll
    for (int off = 1; off < 64; off <<= 1) { int t = __shfl_up(inc, off); if (lane >= off) inc += t; }
    __shared__ int wsum[4];
    if (lane == 63) wsum[wv] = inc;
    __syncthreads();
    int wo = 0;
    for (int w = 0; w < wv; ++w) wo += wsum[w];
    int incl = inc + wo;
    if (tid < NB256) boff[tid] = incl - v;
    if (tid == 255) *totalp = incl;
}
__global__ void scan3_k(const int* __restrict__ excl, const int* __restrict__ boff,
                        int* __restrict__ rowp, int* __restrict__ cursor) {
    int i = blockIdx.x * 256 + threadIdx.x;
    if (i < N_NODES) { int r = excl[i] + boff[i >> 8]; rowp[i] = r; cursor[i] = r; }
}
__global__ void fill_k(const int* __restrict__ srcI, const int* __restrict__ dstI,
                       int* __restrict__ cursor, int* __restrict__ colx) {
    int i = blockIdx.x * 256 + threadIdx.x;
    if (i >= E_EDGES + N_NODES) return;
    int s, d;
    if (i < E_EDGES) { s = srcI[i]; d = dstI[i]; } else { s = i - E_EDGES; d = s; }
    int slot = atomicAdd(&cursor[d], 1);
    colx[slot] = s;
}

// ---------------- MFMA matmul, LDS-staged coalesced epilogue ----------------
__global__ __launch_bounds__(256) void mfma_mm_k(
    const unsigned short* __restrict__ A, const unsigned short* __restrict__ Wt,
    unsigned short* __restrict__ C, int M, int K) {
    __shared__ unsigned short smem[128 * 72 * 2];   // As | Bs; reused as C-tile (128x136)
    unsigned short* As = smem;
    unsigned short* Bs = smem + 128 * 72;
    int tid = threadIdx.x;
    int wave = tid >> 6, lane = tid & 63;
    int wm = wave >> 1, wn = wave & 1;
    int row0 = blockIdx.y * 128, col0 = blockIdx.x * 128;
    int q = lane >> 4, l = lane & 15;
    f32x4 acc[4][4];
#pragma unroll
    for (int a = 0; a < 4; ++a)
#pragma unroll
        for (int b = 0; b < 4; ++b) acc[a][b] = (f32x4){0.f, 0.f, 0.f, 0.f};
    for (int kb = 0; kb < K; kb += 64) {
#pragma unroll
        for (int it = 0; it < 4; ++it) {
            int cid = it * 256 + tid;
            int r = cid >> 3, kc = cid & 7;
            int gr = row0 + r;
            uint4 v = make_uint4(0, 0, 0, 0);
            if (gr < M) v = *(const uint4*)(A + (size_t)gr * K + kb + kc * 8);
            *(uint4*)&As[r * 72 + kc * 8] = v;
            int gn = col0 + r;
            uint4 w = *(const uint4*)(Wt + (size_t)gn * K + kb + kc * 8);
            *(uint4*)&Bs[r * 72 + kc * 8] = w;
        }
        __syncthreads();
#pragma unroll
        for (int ks = 0; ks < 64; ks += 32) {
            bf16x8 af[4], bfr[4];
#pragma unroll
            for (int mt = 0; mt < 4; ++mt)
                af[mt] = *(const bf16x8*)&As[(wm * 64 + mt * 16 + l) * 72 + ks + q * 8];
#pragma unroll
            for (int nt = 0; nt < 4; ++nt)
                bfr[nt] = *(const bf16x8*)&Bs[(wn * 64 + nt * 16 + l) * 72 + ks + q * 8];
#pragma unroll
            for (int mt = 0; mt < 4; ++mt)
#pragma unroll
                for (int nt = 0; nt < 4; ++nt)
                    acc[mt][nt] = __builtin_amdgcn_mfma_f32_16x16x32_bf16(
                        af[mt], bfr[nt], acc[mt][nt], 0, 0, 0);
        }
        __syncthreads();
    }
    // stage C-tile (bf16) in LDS at stride 136 (16B-aligned rows), then uint4 stores
#pragma unroll
    for (int mt = 0; mt < 4; ++mt) {
        int rowb = wm * 64 + mt * 16 + q * 4;
#pragma unroll
        for (int r = 0; r < 4; ++r) {
#pragma unroll
            for (int nt = 0; nt < 4; ++nt)
                smem[(rowb + r) * 136 + wn * 64 + nt * 16 + l] = f2bf(acc[mt][nt][r]);
        }
    }
    __syncthreads();
    int row = tid >> 1, half = tid & 1;
    int grow = row0 + row;
    if (grow < M) {
        unsigned short* crow = C + (size_t)grow * D_F + col0 + half * 64;
        const unsigned short* srow = &smem[row * 136 + half * 64];
#pragma unroll
        for (int i = 0; i < 8; ++i)
            *(uint4*)(crow + i * 8) = *(const uint4*)(srow + i * 8);
    }
}

// ---------------- attention logits ----------------
__global__ __launch_bounds__(256) void att_k(
    const unsigned short* __restrict__ h2, const unsigned short* __restrict__ a_s,
    const unsigned short* __restrict__ a_d, float* __restrict__ alS, float* __restrict__ alD) {
    int tid = threadIdx.x, wave = tid >> 6, lane = tid & 63;
    int n = blockIdx.x * 4 + wave;
    if (n >= N_NODES) return;
    int h = lane >> 4, j = (lane & 15) * 4;
    ushort4 hu = *(const ushort4*)(h2 + (size_t)n * D_F + h * 64 + j);
    ushort4 su = *(const ushort4*)(a_s + h * 64 + j);
    ushort4 du = *(const ushort4*)(a_d + h * 64 + j);
    float h0 = bf2f(hu.x), h1 = bf2f(hu.y), h2v = bf2f(hu.z), h3 = bf2f(hu.w);
    float ps = h0 * bf2f(su.x) + h1 * bf2f(su.y) + h2v * bf2f(su.z) + h3 * bf2f(su.w);
    float pd = h0 * bf2f(du.x) + h1 * bf2f(du.y) + h2v * bf2f(du.z) + h3 * bf2f(du.w);
#pragma unroll
    for (int off = 1; off < 16; off <<= 1) { ps += __shfl_xor(ps, off); pd += __shfl_xor(pd, off); }
    if ((lane & 15) == 0) { alS[n * 4 + h] = ps; alD[n * 4 + h] = pd; }
}

// ---------------- aggregate pre-pass: per-edge exp weights + denominators (no max; |e|<~10) ----------------
__global__ __launch_bounds__(256) void aggpre_k(
    const int* __restrict__ rowp, const int* __restrict__ colx,
    const float* __restrict__ alS, const float* __restrict__ alD,
    float* __restrict__ alphaBuf, float* __restrict__ rinvBuf) {
    int tid = threadIdx.x, wave = tid >> 6, lane = tid & 63;
    int n = blockIdx.x * 4 + wave;
    if (n >= N_NODES) return;
    int start = rowp[n], end = rowp[n + 1];
    float4 ad = *(const float4*)(alD + (size_t)n * 4);
    float l0 = 0.f, l1 = 0.f, l2 = 0.f, l3 = 0.f;
    for (int j = start + lane; j < end; j += 64) {
        int s = colx[j];
        float4 as = *(const float4*)(alS + (size_t)s * 4);
        float e0 = as.x + ad.x; e0 = e0 > 0.f ? e0 : NEG * e0; float x0 = __expf(e0);
        float e1 = as.y + ad.y; e1 = e1 > 0.f ? e1 : NEG * e1; float x1 = __expf(e1);
        float e2 = as.z + ad.z; e2 = e2 > 0.f ? e2 : NEG * e2; float x2 = __expf(e2);
        float e3 = as.w + ad.w; e3 = e3 > 0.f ? e3 : NEG * e3; float x3 = __expf(e3);
        *(float4*)(alphaBuf + (size_t)j * 4) = make_float4(x0, x1, x2, x3);
        l0 += x0; l1 += x1; l2 += x2; l3 += x3;
    }
#pragma unroll
    for (int off = 1; off < 64; off <<= 1) {
        l0 += __shfl_xor(l0, off); l1 += __shfl_xor(l1, off);
        l2 += __shfl_xor(l2, off); l3 += __shfl_xor(l3, off);
    }
    if (lane == 0) {
        *(float4*)(rinvBuf + (size_t)n * 4) = make_float4(
            1.f / (l0 + 1e-16f), 1.f / (l1 + 1e-16f),
            1.f / (l2 + 1e-16f), 1.f / (l3 + 1e-16f));
    }
}

// ---------------- aggregate main: lean gather+fma, scale once at end ----------------
__global__ __launch_bounds__(256) void agg2_k(
    const unsigned short* __restrict__ h2, const int* __restrict__ rowp, const int* __restrict__ colx,
    const float* __restrict__ alphaBuf, const float* __restrict__ rinvBuf,
    const unsigned short* __restrict__ bias, unsigned short* __restrict__ out) {
    int tid = threadIdx.x, wave = tid >> 6, lane = tid & 63;
    int n = blockIdx.x * 4 + wave;
    if (n >= N_NODES) return;
    int start = rowp[n], end = rowp[n + 1];
    int h = lane >> 4;
    float a0 = 0.f, a1 = 0.f, a2 = 0.f, a3 = 0.f;
    int j = start;
    for (; j + 1 < end; j += 2) {
        int s1 = colx[j], s2 = colx[j + 1];
        float w1 = alphaBuf[(size_t)j * 4 + h];
        float w2 = alphaBuf[(size_t)(j + 1) * 4 + h];
        ushort4 u1 = *(const ushort4*)(h2 + (size_t)s1 * D_F + 4 * lane);
        ushort4 u2 = *(const ushort4*)(h2 + (size_t)s2 * D_F + 4 * lane);
        a0 = fmaf(w1, bf2f(u1.x), a0); a0 = fmaf(w2, bf2f(u2.x), a0);
        a1 = fmaf(w1, bf2f(u1.y), a1); a1 = fmaf(w2, bf2f(u2.y), a1);
        a2 = fmaf(w1, bf2f(u1.z), a2); a2 = fmaf(w2, bf2f(u2.z), a2);
        a3 = fmaf(w1, bf2f(u1.w), a3); a3 = fmaf(w2, bf2f(u2.w), a3);
    }
    if (j < end) {
        int s1 = colx[j];
        float w1 = alphaBuf[(size_t)j * 4 + h];
        ushort4 u1 = *(const ushort4*)(h2 + (size_t)s1 * D_F + 4 * lane);
        a0 = fmaf(w1, bf2f(u1.x), a0);
        a1 = fmaf(w1, bf2f(u1.y), a1);
        a2 = fmaf(w1, bf2f(u1.z), a2);
        a3 = fmaf(w1, bf2f(u1.w), a3);
    }
    float rh = rinvBuf[(size_t)n * 4 + h];
    a0 *= rh; a1 *= rh; a2 *= rh; a3 *= rh;
    ushort4 bu = *(const ushort4*)(bias + 4 * lane);
    float v0 = a0 + bf2f(bu.x); v0 = v0 > 0.f ? v0 : __expf(v0) - 1.f;
    float v1 = a1 + bf2f(bu.y); v1 = v1 > 0.f ? v1 : __expf(v1) - 1.f;
    float v2 = a2 + bf2f(bu.z); v2 = v2 > 0.f ? v2 : __expf(v2) - 1.f;
    float v3 = a3 + bf2f(bu.w); v3 = v3 > 0.f ? v3 : __expf(v3) - 1.f;
    ushort4 o;
    o.x = f2bf(v0); o.y = f2bf(v1); o.z = f2bf(v2); o.w = f2bf(v3);
    *(ushort4*)(out + (size_t)n * D_F + 4 * lane) = o;
}

// ---------------- pool ----------------
__global__ __launch_bounds__(256) void pool_k(const unsigned short* __restrict__ h,
                                              const int* __restrict__ batch,
                                              float* __restrict__ part, int* __restrict__ pcnt) {
    __shared__ float sums[GROUPS * D_F];
    __shared__ int cnts[GROUPS];
    int tid = threadIdx.x;
    for (int i = tid; i < GROUPS * D_F; i += 256) sums[i] = 0.f;
    if (tid < GROUPS) cnts[tid] = 0;
    __syncthreads();
    int n0 = blockIdx.x * POOL_CHUNK;
    int n1 = n0 + POOL_CHUNK; if (n1 > N_NODES) n1 = N_NODES;
    for (int n = n0; n < n1; ++n) {
        int b = batch[n];
        sums[b * D_F + tid] += bf2f(h[(size_t)n * D_F + tid]);
        if (tid == 0) cnts[b]++;
    }
    __syncthreads();
    float* po = part + (size_t)blockIdx.x * (GROUPS * D_F);
    for (int i = tid; i < GROUPS * D_F; i += 256) po[i] = sums[i];
    if (tid < GROUPS) pcnt[blockIdx.x * GROUPS + tid] = cnts[tid];
}

// ---------------- reduce ----------------
__global__ __launch_bounds__(256) void reduce_k(const float* __restrict__ part,
                                                const int* __restrict__ pcnt,
                                                float* __restrict__ gsum, int* __restrict__ gcnt) {
    int g = blockIdx.x, c = threadIdx.x;
    float s = 0.f;
    for (int b = 0; b < POOL_BLOCKS; ++b) s += part[(size_t)b * (GROUPS * D_F) + g * D_F + c];
    gsum[g * D_F + c] = s;
    if (threadIdx.x < 64) {
        int lane = threadIdx.x;
        int cn = 0;
        for (int b = lane; b < POOL_BLOCKS; b += 64) cn += pcnt[b * GROUPS + g];
#pragma unroll
        for (int off = 1; off < 64; off <<= 1) cn += __shfl_xor(cn, off);
        if (lane == 0) gcnt[g] = cn;
    }
}

// ---------------- decoder ----------------
__global__ __launch_bounds__(256) void dec_k(const float* __restrict__ gsum, const int* __restrict__ gcnt,
    const unsigned short* __restrict__ canon, const int* __restrict__ flag,
    void* __restrict__ outp) {
    const unsigned short* w1 = canon + OFF_DW1;
    const unsigned short* b1 = canon + OFF_DB1;
    const unsigned short* gam = canon + OFF_DG;
    const unsigned short* bet = canon + OFF_DBE;
    const unsigned short* w2 = canon + OFF_DW2;
    const unsigned short* b2 = canon + OFF_DB2;
    int tid = threadIdx.x, grp = blockIdx.x * 4 + (tid >> 6), lane = tid & 63;
    if (grp >= GROUPS) return;
    float inv = 1.0f / fmaxf((float)gcnt[grp], 1.0f);
    float p[4];
#pragma unroll
    for (int i = 0; i < 4; ++i) p[i] = gsum[grp * D_F + i * 64 + lane] * inv;
    float acc = bf2f(b1[lane]);
#pragma unroll
    for (int i = 0; i < 4; ++i)
        for (int k = 0; k < 64; ++k)
            acc = fmaf(__shfl(p[i], k), bf2f(w1[(i * 64 + k) * 64 + lane]), acc);
    float s = acc;
#pragma unroll
    for (int off = 32; off > 0; off >>= 1) s += __shfl_xor(s, off);
    float mean = s * (1.0f / 64.0f);
    float d = acc - mean;
    float vs = d * d;
#pragma unroll
    for (int off = 32; off > 0; off >>= 1) vs += __shfl_xor(vs, off);
    float rstd = rsqrtf(vs * (1.0f / 64.0f) + LNEPS);
    float val = bf2f(gam[lane]) * d * rstd + bf2f(bet[lane]);
    val = val > 0.f ? val : val * 0.f;
    int cl = (lane < OUT_F) ? lane : 0;
    float acc2 = 0.f;
    for (int k = 0; k < 64; ++k) {
        float wv = bf2f(w2[k * OUT_F + cl]);
        acc2 = fmaf(__shfl(val, k), wv, acc2);
    }
    if (lane < OUT_F) {
        float res = acc2 + bf2f(b2[lane]);
        if (*flag == 0) ((unsigned short*)outp)[grp * OUT_F + lane] = f2bf(res);
        else            ((float*)outp)[grp * OUT_F + lane] = res;
    }
}

extern "C" void kernel_launch(void* const* d_in, const int* in_sizes, int n_in,
                              void* d_out, int out_size, void* d_ws, size_t ws_size,
                              hipStream_t stream) {
    const int* ei    = (const int*)d_in[1];
    const int* batch = (const int*)d_in[2];

    char* p = (char*)d_ws;
    unsigned short* canon = (unsigned short*)p; p += (size_t)CANON_TOT * 2 + 16;
    unsigned short* bufA = (unsigned short*)p; p += (size_t)N_NODES * D_F * 2;
    unsigned short* bufB = (unsigned short*)p; p += (size_t)N_NODES * D_F * 2;
    unsigned short* wt0 = (unsigned short*)p; p += (size_t)64 * 256 * 2;
    unsigned short* wt1 = (unsigned short*)p; p += (size_t)256 * 256 * 2;
    unsigned short* wt2 = (unsigned short*)p; p += (size_t)256 * 256 * 2;
    unsigned short* w1t = (unsigned short*)p; p += (size_t)64 * 128 * 2;
    unsigned short* w2t = (unsigned short*)p; p += (size_t)64 * 64 * 2;
    float* alS  = (float*)p; p += (size_t)N_NODES * 4 * 4;
    float* alD  = (float*)p; p += (size_t)N_NODES * 4 * 4;
    float* rinvB = (float*)p; p += (size_t)N_NODES * 4 * 4;
    float* alphaB = (float*)p; p += (size_t)(E_EDGES + N_NODES) * 4 * 4;   // 13.6 MB
    float* part = (float*)p; p += (size_t)POOL_BLOCKS * GROUPS * D_F * 4;
    int* pcnt   = (int*)p;   p += (size_t)POOL_BLOCKS * GROUPS * 4;
    float* gsum = (float*)p; p += GROUPS * D_F * 4;
    int* gcnt   = (int*)p;   p += 16 * 4;
    int* deg    = (int*)p;   p += (size_t)N_NODES * 4;
    int* excl   = (int*)p;   p += (size_t)N_NODES * 4;
    int* bsums  = (int*)p;   p += 256 * 4;
    int* boff   = (int*)p;   p += 256 * 4;
    int* rowp   = (int*)p;   p += (size_t)(N_NODES + 4) * 4;
    int* cursor = (int*)p;   p += (size_t)N_NODES * 4;
    int* colx   = (int*)p;   p += (size_t)(E_EDGES + N_NODES) * 4;
    int* flag   = (int*)p;   p += 16;

    const int* srcI = ei;
    const int* dstI = ei + E_EDGES;

    SP sp;
    sp.q[0] = d_in[0];
    for (int t = 1; t < 25; ++t) sp.q[t] = d_in[t + 2];

    int nwb = (N_NODES + 3) / 4;
    int nb128 = (N_NODES + 127) / 128;

    flag_k<<<1, 64, 0, stream>>>((const unsigned short*)d_in[5], flag);
    convert_k<<<(CANON_TOT + 255) / 256, 256, 0, stream>>>(sp, flag, canon);
    wt_k<<<256, 256, 0, stream>>>(canon, wt0, wt1, wt2, w1t, w2t);

    enc1_k<<<nb128, 128, 0, stream>>>(canon, w1t, bufB);
    enc2_k<<<nb128, 128, 0, stream>>>(canon, bufB, w2t, bufA);

    deg_init_k<<<NB256, 256, 0, stream>>>(deg);
    deg_count_k<<<(E_EDGES + 255) / 256, 256, 0, stream>>>(dstI, deg);
    scan1_k<<<NB256, 256, 0, stream>>>(deg, excl, bsums);
    scan2_k<<<1, 256, 0, stream>>>(bsums, boff, rowp + N_NODES);
    scan3_k<<<NB256, 256, 0, stream>>>(excl, boff, rowp, cursor);
    fill_k<<<(E_EDGES + N_NODES + 255) / 256, 256, 0, stream>>>(srcI, dstI, cursor, colx);

    dim3 mmg(2, nb128);
    mfma_mm_k<<<mmg, 256, 0, stream>>>(bufA, wt0, bufB, N_NODES, HIDF);
    att_k<<<nwb, 256, 0, stream>>>(bufB, canon + OFF_C0AS, canon + OFF_C0AD, alS, alD);
    aggpre_k<<<nwb, 256, 0, stream>>>(rowp, colx, alS, alD, alphaB, rinvB);
    agg2_k<<<nwb, 256, 0, stream>>>(bufB, rowp, colx, alphaB, rinvB, canon + OFF_C0B, bufA);

    mfma_mm_k<<<mmg, 256, 0, stream>>>(bufA, wt1, bufB, N_NODES, D_F);
    att_k<<<nwb, 256, 0, stream>>>(bufB, canon + OFF_C1AS, canon + OFF_C1AD, alS, alD);
    aggpre_k<<<nwb, 256, 0, stream>>>(rowp, colx, alS, alD, alphaB, rinvB);
    agg2_k<<<nwb, 256, 0, stream>>>(bufB, rowp, colx, alphaB, rinvB, canon + OFF_C1B, bufA);

    mfma_mm_k<<<mmg, 256, 0, stream>>>(bufA, wt2, bufB, N_NODES, D_F);
    att_k<<<nwb, 256, 0, stream>>>(bufB, canon + OFF_C2AS, canon + OFF_C2AD, alS, alD);
    aggpre_k<<<nwb, 256, 0, stream>>>(rowp, colx, alS, alD, alphaB, rinvB);
    agg2_k<<<nwb, 256, 0, stream>>>(bufB, rowp, colx, alphaB, rinvB, canon + OFF_C2B, bufA);

    pool_k<<<POOL_BLOCKS, 256, 0, stream>>>(bufA, batch, part, pcnt);
    reduce_k<<<GROUPS, 256, 0, stream>>>(part, pcnt, gsum, gcnt);
    dec_k<<<2, 256, 0, stream>>>(gsum, gcnt, canon, flag, d_out);
}

// Round 8
// 661.542 us; speedup vs baseline: 1.0625x; 1.0625x over previous
//
#include <hip/hip_runtime.h>
#include <hip/hip_bf16.h>

#define N_NODES 50000
#define E_EDGES 800000
#define IN_F 128
#define HIDF 64
#define HEADS 4
#define OUT_F 40
#define GROUPS 8
#define D_F 256
#define NEG 0.2f
#define LNEPS 1e-5f
#define POOL_CHUNK 128
#define POOL_BLOCKS ((N_NODES + POOL_CHUNK - 1) / POOL_CHUNK)   // 391
#define NB256 ((N_NODES + 255) / 256)                            // 196

// canonical bf16 parameter buffer: element offsets
#define OFF_X    0
#define OFF_EW1  6400000
#define OFF_EB1  6408192
#define OFF_EG   6408256
#define OFF_EBE  6408320
#define OFF_EW2  6408384
#define OFF_EB2  6412480
#define OFF_C0W  6412544
#define OFF_C0AS 6428928
#define OFF_C0AD 6429184
#define OFF_C0B  6429440
#define OFF_C1W  6429696
#define OFF_C1AS 6495232
#define OFF_C1AD 6495488
#define OFF_C1B  6495744
#define OFF_C2W  6496000
#define OFF_C2AS 6561536
#define OFF_C2AD 6561792
#define OFF_C2B  6562048
#define OFF_DW1  6562304
#define OFF_DB1  6578688
#define OFF_DG   6578752
#define OFF_DBE  6578816
#define OFF_DW2  6578880
#define OFF_DB2  6581440
#define CANON_TOT 6581480

__device__ __constant__ int c_off[26] = {
    OFF_X, OFF_EW1, OFF_EB1, OFF_EG, OFF_EBE, OFF_EW2, OFF_EB2,
    OFF_C0W, OFF_C0AS, OFF_C0AD, OFF_C0B,
    OFF_C1W, OFF_C1AS, OFF_C1AD, OFF_C1B,
    OFF_C2W, OFF_C2AS, OFF_C2AD, OFF_C2B,
    OFF_DW1, OFF_DB1, OFF_DG, OFF_DBE, OFF_DW2, OFF_DB2, CANON_TOT};

typedef __attribute__((ext_vector_type(8))) short bf16x8;
typedef __attribute__((ext_vector_type(4))) float f32x4;

__device__ __forceinline__ float bf2f(unsigned short u) {
    union { unsigned int i; float f; } v; v.i = ((unsigned int)u) << 16; return v.f;
}
__device__ __forceinline__ unsigned short f2bf(float f) {
    union { float f; unsigned int i; } v; v.f = f;
    unsigned int r = v.i + 0x7FFF + ((v.i >> 16) & 1);   // RNE
    return (unsigned short)(r >> 16);
}
__device__ __forceinline__ void mac8(float* acc, float w, uint4 u) {
    acc[0] = fmaf(w, bf2f((unsigned short)(u.x & 0xffff)), acc[0]);
    acc[1] = fmaf(w, bf2f((unsigned short)(u.x >> 16)),    acc[1]);
    acc[2] = fmaf(w, bf2f((unsigned short)(u.y & 0xffff)), acc[2]);
    acc[3] = fmaf(w, bf2f((unsigned short)(u.y >> 16)),    acc[3]);
    acc[4] = fmaf(w, bf2f((unsigned short)(u.z & 0xffff)), acc[4]);
    acc[5] = fmaf(w, bf2f((unsigned short)(u.z >> 16)),    acc[5]);
    acc[6] = fmaf(w, bf2f((unsigned short)(u.w & 0xffff)), acc[6]);
    acc[7] = fmaf(w, bf2f((unsigned short)(u.w >> 16)),    acc[7]);
}

// ---------- dtype flag ----------
__global__ void flag_k(const unsigned short* __restrict__ encg, int* __restrict__ flag) {
    if (threadIdx.x == 0 && blockIdx.x == 0) {
        unsigned short a = encg[0], b = encg[1];
        int f = 0;
        if (a == 0x0000 && b == 0x3F80) f = 1;
        *flag = f;
    }
}

// ---------- canonicalize (fast path for x) ----------
struct SP { const void* q[25]; };
__global__ __launch_bounds__(256) void convert_k(SP sp, const int* __restrict__ flag,
                                                 unsigned short* __restrict__ canon) {
    int i = blockIdx.x * 256 + threadIdx.x;
    if (i >= CANON_TOT) return;
    int fl = *flag;
    if (i < OFF_EW1) {   // x tensor: 97% of elements
        canon[i] = fl == 0 ? ((const unsigned short*)sp.q[0])[i]
                           : f2bf(((const float*)sp.q[0])[i]);
        return;
    }
    int t = 1;
    while (i >= c_off[t + 1]) ++t;
    int j = i - c_off[t];
    const void* s = sp.q[t];
    canon[i] = fl == 0 ? ((const unsigned short*)s)[j] : f2bf(((const float*)s)[j]);
}

// ---------- weight transposes ----------
__global__ void wt_k(const unsigned short* __restrict__ canon,
                     unsigned short* __restrict__ wt0, unsigned short* __restrict__ wt1,
                     unsigned short* __restrict__ wt2, unsigned short* __restrict__ w1t,
                     unsigned short* __restrict__ w2t) {
    int i = blockIdx.x * 256 + threadIdx.x;   // 65536 threads
    if (i < 8192) {
        int k = i >> 6, n = i & 63;
        w1t[n * 128 + k] = canon[OFF_EW1 + k * 64 + n];
    }
    if (i < 4096) {
        int k = i >> 6, n = i & 63;
        w2t[n * 64 + k] = canon[OFF_EW2 + k * 64 + n];
    }
    if (i < 16384) {
        int k = i >> 8, n = i & 255;
        wt0[n * 64 + k] = canon[OFF_C0W + i];
    }
    if (i < 65536) {
        int k = i >> 8, n = i & 255;
        wt1[n * 256 + k] = canon[OFF_C1W + i];
        wt2[n * 256 + k] = canon[OFF_C2W + i];
    }
}

// ---------------- encoder stage 1: T1 = relu(LN(x@w1+b1)), MFMA + fused LN ----------------
__global__ __launch_bounds__(128) void enc1_k(const unsigned short* __restrict__ canon,
                                              const unsigned short* __restrict__ w1t,
                                              unsigned short* __restrict__ T1) {
    const unsigned short* x = canon + OFF_X;
    __shared__ unsigned short As[128 * 72];
    __shared__ unsigned short Bs[64 * 72];
    int tid = threadIdx.x, wave = tid >> 6, lane = tid & 63;
    int q = lane >> 4, l = lane & 15;
    int row0 = blockIdx.x * 128;
    f32x4 acc[4][4];
#pragma unroll
    for (int a = 0; a < 4; ++a)
#pragma unroll
        for (int b = 0; b < 4; ++b) acc[a][b] = (f32x4){0.f, 0.f, 0.f, 0.f};
    for (int kb = 0; kb < IN_F; kb += 64) {
#pragma unroll
        for (int it = 0; it < 8; ++it) {
            int cid = it * 128 + tid;
            int r = cid >> 3, kc = cid & 7;
            int gr = row0 + r;
            uint4 v = make_uint4(0, 0, 0, 0);
            if (gr < N_NODES) v = *(const uint4*)(x + (size_t)gr * IN_F + kb + kc * 8);
            *(uint4*)&As[r * 72 + kc * 8] = v;
        }
#pragma unroll
        for (int it = 0; it < 4; ++it) {
            int cid = it * 128 + tid;
            int r = cid >> 3, kc = cid & 7;
            uint4 w = *(const uint4*)(w1t + (size_t)r * IN_F + kb + kc * 8);
            *(uint4*)&Bs[r * 72 + kc * 8] = w;
        }
        __syncthreads();
#pragma unroll
        for (int ks = 0; ks < 64; ks += 32) {
            bf16x8 af[4], bfr[4];
#pragma unroll
            for (int mt = 0; mt < 4; ++mt)
                af[mt] = *(const bf16x8*)&As[(wave * 64 + mt * 16 + l) * 72 + ks + q * 8];
#pragma unroll
            for (int nt = 0; nt < 4; ++nt)
                bfr[nt] = *(const bf16x8*)&Bs[(nt * 16 + l) * 72 + ks + q * 8];
#pragma unroll
            for (int mt = 0; mt < 4; ++mt)
#pragma unroll
                for (int nt = 0; nt < 4; ++nt)
                    acc[mt][nt] = __builtin_amdgcn_mfma_f32_16x16x32_bf16(
                        af[mt], bfr[nt], acc[mt][nt], 0, 0, 0);
        }
        __syncthreads();
    }
    float b1c[4], gc[4], bec[4];
#pragma unroll
    for (int nt = 0; nt < 4; ++nt) {
        int c = nt * 16 + l;
        b1c[nt] = bf2f(canon[OFF_EB1 + c]);
        gc[nt]  = bf2f(canon[OFF_EG + c]);
        bec[nt] = bf2f(canon[OFF_EBE + c]);
    }
#pragma unroll
    for (int mt = 0; mt < 4; ++mt) {
#pragma unroll
        for (int r = 0; r < 4; ++r) {
            int grow = row0 + wave * 64 + mt * 16 + q * 4 + r;
            float v0 = acc[mt][0][r] + b1c[0];
            float v1 = acc[mt][1][r] + b1c[1];
            float v2 = acc[mt][2][r] + b1c[2];
            float v3 = acc[mt][3][r] + b1c[3];
            float s = v0 + v1 + v2 + v3;
#pragma unroll
            for (int off = 1; off < 16; off <<= 1) s += __shfl_xor(s, off);
            float mean = s * (1.0f / 64.0f);
            float d0 = v0 - mean, d1 = v1 - mean, d2 = v2 - mean, d3 = v3 - mean;
            float vs = d0 * d0 + d1 * d1 + d2 * d2 + d3 * d3;
#pragma unroll
            for (int off = 1; off < 16; off <<= 1) vs += __shfl_xor(vs, off);
            float rstd = rsqrtf(vs * (1.0f / 64.0f) + LNEPS);
            if (grow < N_NODES) {
                unsigned short* trow = T1 + (size_t)grow * HIDF;
                float o0 = gc[0] * d0 * rstd + bec[0]; o0 = fmaxf(o0, 0.f);
                float o1 = gc[1] * d1 * rstd + bec[1]; o1 = fmaxf(o1, 0.f);
                float o2 = gc[2] * d2 * rstd + bec[2]; o2 = fmaxf(o2, 0.f);
                float o3 = gc[3] * d3 * rstd + bec[3]; o3 = fmaxf(o3, 0.f);
                trow[l] = f2bf(o0); trow[16 + l] = f2bf(o1);
                trow[32 + l] = f2bf(o2); trow[48 + l] = f2bf(o3);
            }
        }
    }
}

// ---------------- encoder stage 2: h0 = T1 @ w2 + b2 ----------------
__global__ __launch_bounds__(128) void enc2_k(const unsigned short* __restrict__ canon,
                                              const unsigned short* __restrict__ T1,
                                              const unsigned short* __restrict__ w2t,
                                              unsigned short* __restrict__ h0) {
    __shared__ unsigned short As[128 * 72];
    __shared__ unsigned short Bs[64 * 72];
    int tid = threadIdx.x, wave = tid >> 6, lane = tid & 63;
    int q = lane >> 4, l = lane & 15;
    int row0 = blockIdx.x * 128;
    f32x4 acc[4][4];
#pragma unroll
    for (int a = 0; a < 4; ++a)
#pragma unroll
        for (int b = 0; b < 4; ++b) acc[a][b] = (f32x4){0.f, 0.f, 0.f, 0.f};
#pragma unroll
    for (int it = 0; it < 8; ++it) {
        int cid = it * 128 + tid;
        int r = cid >> 3, kc = cid & 7;
        int gr = row0 + r;
        uint4 v = make_uint4(0, 0, 0, 0);
        if (gr < N_NODES) v = *(const uint4*)(T1 + (size_t)gr * HIDF + kc * 8);
        *(uint4*)&As[r * 72 + kc * 8] = v;
    }
#pragma unroll
    for (int it = 0; it < 4; ++it) {
        int cid = it * 128 + tid;
        int r = cid >> 3, kc = cid & 7;
        uint4 w = *(const uint4*)(w2t + (size_t)r * HIDF + kc * 8);
        *(uint4*)&Bs[r * 72 + kc * 8] = w;
    }
    __syncthreads();
#pragma unroll
    for (int ks = 0; ks < 64; ks += 32) {
        bf16x8 af[4], bfr[4];
#pragma unroll
        for (int mt = 0; mt < 4; ++mt)
            af[mt] = *(const bf16x8*)&As[(wave * 64 + mt * 16 + l) * 72 + ks + q * 8];
#pragma unroll
        for (int nt = 0; nt < 4; ++nt)
            bfr[nt] = *(const bf16x8*)&Bs[(nt * 16 + l) * 72 + ks + q * 8];
#pragma unroll
        for (int mt = 0; mt < 4; ++mt)
#pragma unroll
            for (int nt = 0; nt < 4; ++nt)
                acc[mt][nt] = __builtin_amdgcn_mfma_f32_16x16x32_bf16(
                    af[mt], bfr[nt], acc[mt][nt], 0, 0, 0);
    }
    float b2c[4];
#pragma unroll
    for (int nt = 0; nt < 4; ++nt) b2c[nt] = bf2f(canon[OFF_EB2 + nt * 16 + l]);
#pragma unroll
    for (int mt = 0; mt < 4; ++mt) {
#pragma unroll
        for (int r = 0; r < 4; ++r) {
            int grow = row0 + wave * 64 + mt * 16 + q * 4 + r;
            if (grow < N_NODES) {
                unsigned short* hrow = h0 + (size_t)grow * HIDF;
#pragma unroll
                for (int nt = 0; nt < 4; ++nt)
                    hrow[nt * 16 + l] = f2bf(acc[mt][nt][r] + b2c[nt]);
            }
        }
    }
}

// ---------------- CSR build ----------------
__global__ void deg_init_k(int* __restrict__ deg) {
    int i = blockIdx.x * 256 + threadIdx.x;
    if (i < N_NODES) deg[i] = 1;
}
__global__ void deg_count_k(const int* __restrict__ dstI, int* __restrict__ deg) {
    int i = blockIdx.x * 256 + threadIdx.x;
    if (i < E_EDGES) atomicAdd(&deg[dstI[i]], 1);
}
__global__ __launch_bounds__(256) void scan1_k(const int* __restrict__ deg, int* __restrict__ excl,
                                               int* __restrict__ bsums) {
    int tid = threadIdx.x, lane = tid & 63, wv = tid >> 6;
    int gid = blockIdx.x * 256 + tid;
    int v = (gid < N_NODES) ? deg[gid] : 0;
    int inc = v;
#pragma unroll
    for (int off = 1; off < 64; off <<= 1) { int t = __shfl_up(inc, off); if (lane >= off) inc += t; }
    __shared__ int wsum[4];
    if (lane == 63) wsum[wv] = inc;
    __syncthreads();
    int wo = 0;
    for (int w = 0; w < wv; ++w) wo += wsum[w];
    int incl = inc + wo;
    if (gid < N_NODES) excl[gid] = incl - v;
    if (tid == 255) bsums[blockIdx.x] = incl;
}
__global__ __launch_bounds__(256) void scan2_k(const int* __restrict__ bsums, int* __restrict__ boff,
                                               int* __restrict__ totalp) {
    int tid = threadIdx.x, lane = tid & 63, wv = tid >> 6;
    int v = (tid < NB256) ? bsums[tid] : 0;
    int inc = v;
#pragma unroll
    for (int off = 1; off < 64; off <<= 1) { int t = __shfl_up(inc, off); if (lane >= off) inc += t; }
    __shared__ int wsum[4];
    if (lane == 63) wsum[wv] = inc;
    __syncthreads();
    int wo = 0;
    for (int w = 0; w < wv; ++w) wo += wsum[w];
    int incl = inc + wo;
    if (tid < NB256) boff[tid] = incl - v;
    if (tid == 255) *totalp = incl;
}
__global__ void scan3_k(const int* __restrict__ excl, const int* __restrict__ boff,
                        int* __restrict__ rowp, int* __restrict__ cursor) {
    int i = blockIdx.x * 256 + threadIdx.x;
    if (i < N_NODES) { int r = excl[i] + boff[i >> 8]; rowp[i] = r; cursor[i] = r; }
}
__global__ void fill_k(const int* __restrict__ srcI, const int* __restrict__ dstI,
                       int* __restrict__ cursor, int* __restrict__ colx) {
    int i = blockIdx.x * 256 + threadIdx.x;
    if (i >= E_EDGES + N_NODES) return;
    int s, d;
    if (i < E_EDGES) { s = srcI[i]; d = dstI[i]; } else { s = i - E_EDGES; d = s; }
    int slot = atomicAdd(&cursor[d], 1);
    colx[slot] = s;
}

// ---------------- MFMA matmul + fused attention logits ----------------
__global__ __launch_bounds__(256) void mfma_mm_k(
    const unsigned short* __restrict__ A, const unsigned short* __restrict__ Wt,
    unsigned short* __restrict__ C, int M, int K,
    const unsigned short* __restrict__ aSv, const unsigned short* __restrict__ aDv,
    float* __restrict__ alS, float* __restrict__ alD) {
    __shared__ unsigned short smem[128 * 72 * 2];   // As | Bs; reused as C-tile (128x136)
    unsigned short* As = smem;
    unsigned short* Bs = smem + 128 * 72;
    int tid = threadIdx.x;
    int wave = tid >> 6, lane = tid & 63;
    int wm = wave >> 1, wn = wave & 1;
    int row0 = blockIdx.y * 128, col0 = blockIdx.x * 128;
    int q = lane >> 4, l = lane & 15;
    f32x4 acc[4][4];
#pragma unroll
    for (int a = 0; a < 4; ++a)
#pragma unroll
        for (int b = 0; b < 4; ++b) acc[a][b] = (f32x4){0.f, 0.f, 0.f, 0.f};
    for (int kb = 0; kb < K; kb += 64) {
#pragma unroll
        for (int it = 0; it < 4; ++it) {
            int cid = it * 256 + tid;
            int r = cid >> 3, kc = cid & 7;
            int gr = row0 + r;
            uint4 v = make_uint4(0, 0, 0, 0);
            if (gr < M) v = *(const uint4*)(A + (size_t)gr * K + kb + kc * 8);
            *(uint4*)&As[r * 72 + kc * 8] = v;
            int gn = col0 + r;
            uint4 w = *(const uint4*)(Wt + (size_t)gn * K + kb + kc * 8);
            *(uint4*)&Bs[r * 72 + kc * 8] = w;
        }
        __syncthreads();
#pragma unroll
        for (int ks = 0; ks < 64; ks += 32) {
            bf16x8 af[4], bfr[4];
#pragma unroll
            for (int mt = 0; mt < 4; ++mt)
                af[mt] = *(const bf16x8*)&As[(wm * 64 + mt * 16 + l) * 72 + ks + q * 8];
#pragma unroll
            for (int nt = 0; nt < 4; ++nt)
                bfr[nt] = *(const bf16x8*)&Bs[(wn * 64 + nt * 16 + l) * 72 + ks + q * 8];
#pragma unroll
            for (int mt = 0; mt < 4; ++mt)
#pragma unroll
                for (int nt = 0; nt < 4; ++nt)
                    acc[mt][nt] = __builtin_amdgcn_mfma_f32_16x16x32_bf16(
                        af[mt], bfr[nt], acc[mt][nt], 0, 0, 0);
        }
        __syncthreads();
    }
    // stage C-tile (bf16) in LDS at stride 136, then coalesced stores
#pragma unroll
    for (int mt = 0; mt < 4; ++mt) {
        int rowb = wm * 64 + mt * 16 + q * 4;
#pragma unroll
        for (int r = 0; r < 4; ++r) {
#pragma unroll
            for (int nt = 0; nt < 4; ++nt)
                smem[(rowb + r) * 136 + wn * 64 + nt * 16 + l] = f2bf(acc[mt][nt][r]);
        }
    }
    __syncthreads();
    int row = tid >> 1, half = tid & 1;
    int grow = row0 + row;
    if (grow < M) {
        unsigned short* crow = C + (size_t)grow * D_F + col0 + half * 64;
        const unsigned short* srow = &smem[row * 136 + half * 64];
#pragma unroll
        for (int i = 0; i < 8; ++i)
            *(uint4*)(crow + i * 8) = *(const uint4*)(srow + i * 8);
        // fused attention logits: this thread owns head = col0/64 + half (64 channels)
        int head = (col0 >> 6) + half;
        const unsigned short* av = aSv + head * 64;
        const unsigned short* dv = aDv + head * 64;
        float ps = 0.f, pd = 0.f;
#pragma unroll
        for (int k = 0; k < 64; ++k) {
            float hv = bf2f(srow[k]);
            ps = fmaf(hv, bf2f(av[k]), ps);
            pd = fmaf(hv, bf2f(dv[k]), pd);
        }
        alS[(size_t)grow * 4 + head] = ps;
        alD[(size_t)grow * 4 + head] = pd;
    }
}

// ---------------- aggregate pre-pass: bf16 per-edge exp weights + fp32 denominators ----------------
__global__ __launch_bounds__(256) void aggpre_k(
    const int* __restrict__ rowp, const int* __restrict__ colx,
    const float* __restrict__ alS, const float* __restrict__ alD,
    unsigned short* __restrict__ alphaBuf, float* __restrict__ rinvBuf) {
    int tid = threadIdx.x, wave = tid >> 6, lane = tid & 63;
    int n = blockIdx.x * 4 + wave;
    if (n >= N_NODES) return;
    int start = rowp[n], end = rowp[n + 1];
    float4 ad = *(const float4*)(alD + (size_t)n * 4);
    float l0 = 0.f, l1 = 0.f, l2 = 0.f, l3 = 0.f;
    for (int j = start + lane; j < end; j += 64) {
        int s = colx[j];
        float4 as = *(const float4*)(alS + (size_t)s * 4);
        float e0 = as.x + ad.x; e0 = e0 > 0.f ? e0 : NEG * e0;
        float e1 = as.y + ad.y; e1 = e1 > 0.f ? e1 : NEG * e1;
        float e2 = as.z + ad.z; e2 = e2 > 0.f ? e2 : NEG * e2;
        float e3 = as.w + ad.w; e3 = e3 > 0.f ? e3 : NEG * e3;
        ushort4 a;
        a.x = f2bf(__expf(e0)); a.y = f2bf(__expf(e1));
        a.z = f2bf(__expf(e2)); a.w = f2bf(__expf(e3));
        *(ushort4*)(alphaBuf + (size_t)j * 4) = a;
        l0 += bf2f(a.x); l1 += bf2f(a.y); l2 += bf2f(a.z); l3 += bf2f(a.w);
    }
#pragma unroll
    for (int off = 1; off < 64; off <<= 1) {
        l0 += __shfl_xor(l0, off); l1 += __shfl_xor(l1, off);
        l2 += __shfl_xor(l2, off); l3 += __shfl_xor(l3, off);
    }
    if (lane == 0) {
        *(float4*)(rinvBuf + (size_t)n * 4) = make_float4(
            1.f / (l0 + 1e-16f), 1.f / (l1 + 1e-16f),
            1.f / (l2 + 1e-16f), 1.f / (l3 + 1e-16f));
    }
}

// ---------------- aggregate main: 16B/lane gather, 2 edges per wave-inst ----------------
__global__ __launch_bounds__(256) void agg2_k(
    const unsigned short* __restrict__ h2, const int* __restrict__ rowp, const int* __restrict__ colx,
    const unsigned short* __restrict__ alphaBuf, const float* __restrict__ rinvBuf,
    const unsigned short* __restrict__ bias, unsigned short* __restrict__ out) {
    int tid = threadIdx.x, wave = tid >> 6, lane = tid & 63;
    int n = blockIdx.x * 4 + wave;
    if (n >= N_NODES) return;
    int start = rowp[n], end = rowp[n + 1];
    int e = lane >> 5;           // edge parity for this half-wave
    int c = lane & 31;           // 8-channel group: channels c*8..c*8+7
    int head = c >> 3;
    float acc[8] = {};
    int j = start;
    for (; j + 3 < end; j += 4) {
        int j1 = j + e, j2 = j + 2 + e;
        int s1 = colx[j1], s2 = colx[j2];
        float w1 = bf2f(alphaBuf[(size_t)j1 * 4 + head]);
        float w2 = bf2f(alphaBuf[(size_t)j2 * 4 + head]);
        uint4 u1 = *(const uint4*)(h2 + (size_t)s1 * D_F + c * 8);
        uint4 u2 = *(const uint4*)(h2 + (size_t)s2 * D_F + c * 8);
        mac8(acc, w1, u1);
        mac8(acc, w2, u2);
    }
    for (; j < end; j += 2) {
        int j1 = j + e;
        int jc = j1 < end ? j1 : end - 1;
        int s1 = colx[jc];
        float w1 = (j1 < end) ? bf2f(alphaBuf[(size_t)jc * 4 + head]) : 0.f;
        uint4 u1 = *(const uint4*)(h2 + (size_t)s1 * D_F + c * 8);
        mac8(acc, w1, u1);
    }
#pragma unroll
    for (int k = 0; k < 8; ++k) acc[k] += __shfl_xor(acc[k], 32);
    if (lane < 32) {
        float rh = rinvBuf[(size_t)n * 4 + head];
        uint4 bu = *(const uint4*)(bias + c * 8);
        float b[8];
        b[0] = bf2f((unsigned short)(bu.x & 0xffff)); b[1] = bf2f((unsigned short)(bu.x >> 16));
        b[2] = bf2f((unsigned short)(bu.y & 0xffff)); b[3] = bf2f((unsigned short)(bu.y >> 16));
        b[4] = bf2f((unsigned short)(bu.z & 0xffff)); b[5] = bf2f((unsigned short)(bu.z >> 16));
        b[6] = bf2f((unsigned short)(bu.w & 0xffff)); b[7] = bf2f((unsigned short)(bu.w >> 16));
        unsigned int o[4];
#pragma unroll
        for (int k = 0; k < 4; ++k) {
            float v0 = acc[2 * k] * rh + b[2 * k];
            float v1 = acc[2 * k + 1] * rh + b[2 * k + 1];
            v0 = v0 > 0.f ? v0 : __expf(v0) - 1.f;
            v1 = v1 > 0.f ? v1 : __expf(v1) - 1.f;
            o[k] = (unsigned int)f2bf(v0) | ((unsigned int)f2bf(v1) << 16);
        }
        *(uint4*)(out + (size_t)n * D_F + c * 8) = make_uint4(o[0], o[1], o[2], o[3]);
    }
}

// ---------------- pool ----------------
__global__ __launch_bounds__(256) void pool_k(const unsigned short* __restrict__ h,
                                              const int* __restrict__ batch,
                                              float* __restrict__ part, int* __restrict__ pcnt) {
    __shared__ float sums[GROUPS * D_F];
    __shared__ int cnts[GROUPS];
    int tid = threadIdx.x;
    for (int i = tid; i < GROUPS * D_F; i += 256) sums[i] = 0.f;
    if (tid < GROUPS) cnts[tid] = 0;
    __syncthreads();
    int n0 = blockIdx.x * POOL_CHUNK;
    int n1 = n0 + POOL_CHUNK; if (n1 > N_NODES) n1 = N_NODES;
    for (int n = n0; n < n1; ++n) {
        int b = batch[n];
        sums[b * D_F + tid] += bf2f(h[(size_t)n * D_F + tid]);
        if (tid == 0) cnts[b]++;
    }
    __syncthreads();
    float* po = part + (size_t)blockIdx.x * (GROUPS * D_F);
    for (int i = tid; i < GROUPS * D_F; i += 256) po[i] = sums[i];
    if (tid < GROUPS) pcnt[blockIdx.x * GROUPS + tid] = cnts[tid];
}

// ---------------- reduce ----------------
__global__ __launch_bounds__(256) void reduce_k(const float* __restrict__ part,
                                                const int* __restrict__ pcnt,
                                                float* __restrict__ gsum, int* __restrict__ gcnt) {
    int g = blockIdx.x, c = threadIdx.x;
    float s = 0.f;
    for (int b = 0; b < POOL_BLOCKS; ++b) s += part[(size_t)b * (GROUPS * D_F) + g * D_F + c];
    gsum[g * D_F + c] = s;
    if (threadIdx.x < 64) {
        int lane = threadIdx.x;
        int cn = 0;
        for (int b = lane; b < POOL_BLOCKS; b += 64) cn += pcnt[b * GROUPS + g];
#pragma unroll
        for (int off = 1; off < 64; off <<= 1) cn += __shfl_xor(cn, off);
        if (lane == 0) gcnt[g] = cn;
    }
}

// ---------------- decoder ----------------
__global__ __launch_bounds__(256) void dec_k(const float* __restrict__ gsum, const int* __restrict__ gcnt,
    const unsigned short* __restrict__ canon, const int* __restrict__ flag,
    void* __restrict__ outp) {
    const unsigned short* w1 = canon + OFF_DW1;
    const unsigned short* b1 = canon + OFF_DB1;
    const unsigned short* gam = canon + OFF_DG;
    const unsigned short* bet = canon + OFF_DBE;
    const unsigned short* w2 = canon + OFF_DW2;
    const unsigned short* b2 = canon + OFF_DB2;
    int tid = threadIdx.x, grp = blockIdx.x * 4 + (tid >> 6), lane = tid & 63;
    if (grp >= GROUPS) return;
    float inv = 1.0f / fmaxf((float)gcnt[grp], 1.0f);
    float p[4];
#pragma unroll
    for (int i = 0; i < 4; ++i) p[i] = gsum[grp * D_F + i * 64 + lane] * inv;
    float acc = bf2f(b1[lane]);
#pragma unroll
    for (int i = 0; i < 4; ++i)
        for (int k = 0; k < 64; ++k)
            acc = fmaf(__shfl(p[i], k), bf2f(w1[(i * 64 + k) * 64 + lane]), acc);
    float s = acc;
#pragma unroll
    for (int off = 32; off > 0; off >>= 1) s += __shfl_xor(s, off);
    float mean = s * (1.0f / 64.0f);
    float d = acc - mean;
    float vs = d * d;
#pragma unroll
    for (int off = 32; off > 0; off >>= 1) vs += __shfl_xor(vs, off);
    float rstd = rsqrtf(vs * (1.0f / 64.0f) + LNEPS);
    float val = bf2f(gam[lane]) * d * rstd + bf2f(bet[lane]);
    val = val > 0.f ? val : val * 0.f;
    int cl = (lane < OUT_F) ? lane : 0;
    float acc2 = 0.f;
    for (int k = 0; k < 64; ++k) {
        float wv = bf2f(w2[k * OUT_F + cl]);
        acc2 = fmaf(__shfl(val, k), wv, acc2);
    }
    if (lane < OUT_F) {
        float res = acc2 + bf2f(b2[lane]);
        if (*flag == 0) ((unsigned short*)outp)[grp * OUT_F + lane] = f2bf(res);
        else            ((float*)outp)[grp * OUT_F + lane] = res;
    }
}

extern "C" void kernel_launch(void* const* d_in, const int* in_sizes, int n_in,
                              void* d_out, int out_size, void* d_ws, size_t ws_size,
                              hipStream_t stream) {
    const int* ei    = (const int*)d_in[1];
    const int* batch = (const int*)d_in[2];

    char* p = (char*)d_ws;
    unsigned short* canon = (unsigned short*)p; p += (size_t)CANON_TOT * 2 + 16;
    unsigned short* bufA = (unsigned short*)p; p += (size_t)N_NODES * D_F * 2;
    unsigned short* bufB = (unsigned short*)p; p += (size_t)N_NODES * D_F * 2;
    unsigned short* wt0 = (unsigned short*)p; p += (size_t)64 * 256 * 2;
    unsigned short* wt1 = (unsigned short*)p; p += (size_t)256 * 256 * 2;
    unsigned short* wt2 = (unsigned short*)p; p += (size_t)256 * 256 * 2;
    unsigned short* w1t = (unsigned short*)p; p += (size_t)64 * 128 * 2;
    unsigned short* w2t = (unsigned short*)p; p += (size_t)64 * 64 * 2;
    float* alS  = (float*)p; p += (size_t)N_NODES * 4 * 4;
    float* alD  = (float*)p; p += (size_t)N_NODES * 4 * 4;
    float* rinvB = (float*)p; p += (size_t)N_NODES * 4 * 4;
    unsigned short* alphaB = (unsigned short*)p; p += (size_t)(E_EDGES + N_NODES) * 4 * 2;  // 6.8 MB
    float* part = (float*)p; p += (size_t)POOL_BLOCKS * GROUPS * D_F * 4;
    int* pcnt   = (int*)p;   p += (size_t)POOL_BLOCKS * GROUPS * 4;
    float* gsum = (float*)p; p += GROUPS * D_F * 4;
    int* gcnt   = (int*)p;   p += 16 * 4;
    int* deg    = (int*)p;   p += (size_t)N_NODES * 4;
    int* excl   = (int*)p;   p += (size_t)N_NODES * 4;
    int* bsums  = (int*)p;   p += 256 * 4;
    int* boff   = (int*)p;   p += 256 * 4;
    int* rowp   = (int*)p;   p += (size_t)(N_NODES + 4) * 4;
    int* cursor = (int*)p;   p += (size_t)N_NODES * 4;
    int* colx   = (int*)p;   p += (size_t)(E_EDGES + N_NODES) * 4;
    int* flag   = (int*)p;   p += 16;

    const int* srcI = ei;
    const int* dstI = ei + E_EDGES;

    SP sp;
    sp.q[0] = d_in[0];
    for (int t = 1; t < 25; ++t) sp.q[t] = d_in[t + 2];

    int nwb = (N_NODES + 3) / 4;
    int nb128 = (N_NODES + 127) / 128;

    flag_k<<<1, 64, 0, stream>>>((const unsigned short*)d_in[5], flag);
    convert_k<<<(CANON_TOT + 255) / 256, 256, 0, stream>>>(sp, flag, canon);
    wt_k<<<256, 256, 0, stream>>>(canon, wt0, wt1, wt2, w1t, w2t);

    enc1_k<<<nb128, 128, 0, stream>>>(canon, w1t, bufB);
    enc2_k<<<nb128, 128, 0, stream>>>(canon, bufB, w2t, bufA);

    deg_init_k<<<NB256, 256, 0, stream>>>(deg);
    deg_count_k<<<(E_EDGES + 255) / 256, 256, 0, stream>>>(dstI, deg);
    scan1_k<<<NB256, 256, 0, stream>>>(deg, excl, bsums);
    scan2_k<<<1, 256, 0, stream>>>(bsums, boff, rowp + N_NODES);
    scan3_k<<<NB256, 256, 0, stream>>>(excl, boff, rowp, cursor);
    fill_k<<<(E_EDGES + N_NODES + 255) / 256, 256, 0, stream>>>(srcI, dstI, cursor, colx);

    dim3 mmg(2, nb128);
    mfma_mm_k<<<mmg, 256, 0, stream>>>(bufA, wt0, bufB, N_NODES, HIDF,
                                       canon + OFF_C0AS, canon + OFF_C0AD, alS, alD);
    aggpre_k<<<nwb, 256, 0, stream>>>(rowp, colx, alS, alD, alphaB, rinvB);
    agg2_k<<<nwb, 256, 0, stream>>>(bufB, rowp, colx, alphaB, rinvB, canon + OFF_C0B, bufA);

    mfma_mm_k<<<mmg, 256, 0, stream>>>(bufA, wt1, bufB, N_NODES, D_F,
                                       canon + OFF_C1AS, canon + OFF_C1AD, alS, alD);
    aggpre_k<<<nwb, 256, 0, stream>>>(rowp, colx, alS, alD, alphaB, rinvB);
    agg2_k<<<nwb, 256, 0, stream>>>(bufB, rowp, colx, alphaB, rinvB, canon + OFF_C1B, bufA);

    mfma_mm_k<<<mmg, 256, 0, stream>>>(bufA, wt2, bufB, N_NODES, D_F,
                                       canon + OFF_C2AS, canon + OFF_C2AD, alS, alD);
    aggpre_k<<<nwb, 256, 0, stream>>>(rowp, colx, alS, alD, alphaB, rinvB);
    agg2_k<<<nwb, 256, 0, stream>>>(bufB, rowp, colx, alphaB, rinvB, canon + OFF_C2B, bufA);

    pool_k<<<POOL_BLOCKS, 256, 0, stream>>>(bufA, batch, part, pcnt);
    reduce_k<<<GROUPS, 256, 0, stream>>>(part, pcnt, gsum, gcnt);
    dec_k<<<2, 256, 0, stream>>>(gsum, gcnt, canon, flag, d_out);
}

// Round 9
// 632.014 us; speedup vs baseline: 1.1121x; 1.0467x over previous
//
#include <hip/hip_runtime.h>
#include <hip/hip_bf16.h>

#define N_NODES 50000
#define E_EDGES 800000
#define IN_F 128
#define HIDF 64
#define HEADS 4
#define OUT_F 40
#define GROUPS 8
#define D_F 256
#define NEG 0.2f
#define LNEPS 1e-5f
#define POOL_CHUNK 128
#define POOL_BLOCKS ((N_NODES + POOL_CHUNK - 1) / POOL_CHUNK)   // 391
#define NB256 ((N_NODES + 255) / 256)                            // 196

// canonical bf16 parameter buffer: element offsets
#define OFF_X    0
#define OFF_EW1  6400000
#define OFF_EB1  6408192
#define OFF_EG   6408256
#define OFF_EBE  6408320
#define OFF_EW2  6408384
#define OFF_EB2  6412480
#define OFF_C0W  6412544
#define OFF_C0AS 6428928
#define OFF_C0AD 6429184
#define OFF_C0B  6429440
#define OFF_C1W  6429696
#define OFF_C1AS 6495232
#define OFF_C1AD 6495488
#define OFF_C1B  6495744
#define OFF_C2W  6496000
#define OFF_C2AS 6561536
#define OFF_C2AD 6561792
#define OFF_C2B  6562048
#define OFF_DW1  6562304
#define OFF_DB1  6578688
#define OFF_DG   6578752
#define OFF_DBE  6578816
#define OFF_DW2  6578880
#define OFF_DB2  6581440
#define CANON_TOT 6581480

__device__ __constant__ int c_off[26] = {
    OFF_X, OFF_EW1, OFF_EB1, OFF_EG, OFF_EBE, OFF_EW2, OFF_EB2,
    OFF_C0W, OFF_C0AS, OFF_C0AD, OFF_C0B,
    OFF_C1W, OFF_C1AS, OFF_C1AD, OFF_C1B,
    OFF_C2W, OFF_C2AS, OFF_C2AD, OFF_C2B,
    OFF_DW1, OFF_DB1, OFF_DG, OFF_DBE, OFF_DW2, OFF_DB2, CANON_TOT};

typedef __attribute__((ext_vector_type(8))) short bf16x8;
typedef __attribute__((ext_vector_type(4))) float f32x4;

__device__ __forceinline__ float bf2f(unsigned short u) {
    union { unsigned int i; float f; } v; v.i = ((unsigned int)u) << 16; return v.f;
}
__device__ __forceinline__ unsigned short f2bf(float f) {
    union { float f; unsigned int i; } v; v.f = f;
    unsigned int r = v.i + 0x7FFF + ((v.i >> 16) & 1);   // RNE
    return (unsigned short)(r >> 16);
}
__device__ __forceinline__ void mac8(float* acc, float w, uint4 u) {
    acc[0] = fmaf(w, bf2f((unsigned short)(u.x & 0xffff)), acc[0]);
    acc[1] = fmaf(w, bf2f((unsigned short)(u.x >> 16)),    acc[1]);
    acc[2] = fmaf(w, bf2f((unsigned short)(u.y & 0xffff)), acc[2]);
    acc[3] = fmaf(w, bf2f((unsigned short)(u.y >> 16)),    acc[3]);
    acc[4] = fmaf(w, bf2f((unsigned short)(u.z & 0xffff)), acc[4]);
    acc[5] = fmaf(w, bf2f((unsigned short)(u.z >> 16)),    acc[5]);
    acc[6] = fmaf(w, bf2f((unsigned short)(u.w & 0xffff)), acc[6]);
    acc[7] = fmaf(w, bf2f((unsigned short)(u.w >> 16)),    acc[7]);
}

// ---------- dtype flag ----------
__global__ void flag_k(const unsigned short* __restrict__ encg, int* __restrict__ flag) {
    if (threadIdx.x == 0 && blockIdx.x == 0) {
        unsigned short a = encg[0], b = encg[1];
        int f = 0;
        if (a == 0x0000 && b == 0x3F80) f = 1;
        *flag = f;
    }
}

// ---------- canonicalize (fast path for x) ----------
struct SP { const void* q[25]; };
__global__ __launch_bounds__(256) void convert_k(SP sp, const int* __restrict__ flag,
                                                 unsigned short* __restrict__ canon) {
    int i = blockIdx.x * 256 + threadIdx.x;
    if (i >= CANON_TOT) return;
    int fl = *flag;
    if (i < OFF_EW1) {
        canon[i] = fl == 0 ? ((const unsigned short*)sp.q[0])[i]
                           : f2bf(((const float*)sp.q[0])[i]);
        return;
    }
    int t = 1;
    while (i >= c_off[t + 1]) ++t;
    int j = i - c_off[t];
    const void* s = sp.q[t];
    canon[i] = fl == 0 ? ((const unsigned short*)s)[j] : f2bf(((const float*)s)[j]);
}

// ---------- weight transposes ----------
__global__ void wt_k(const unsigned short* __restrict__ canon,
                     unsigned short* __restrict__ wt0, unsigned short* __restrict__ wt1,
                     unsigned short* __restrict__ wt2, unsigned short* __restrict__ w1t,
                     unsigned short* __restrict__ w2t) {
    int i = blockIdx.x * 256 + threadIdx.x;   // 65536 threads
    if (i < 8192) {
        int k = i >> 6, n = i & 63;
        w1t[n * 128 + k] = canon[OFF_EW1 + k * 64 + n];
    }
    if (i < 4096) {
        int k = i >> 6, n = i & 63;
        w2t[n * 64 + k] = canon[OFF_EW2 + k * 64 + n];
    }
    if (i < 16384) {
        int k = i >> 8, n = i & 255;
        wt0[n * 64 + k] = canon[OFF_C0W + i];
    }
    if (i < 65536) {
        int k = i >> 8, n = i & 255;
        wt1[n * 256 + k] = canon[OFF_C1W + i];
        wt2[n * 256 + k] = canon[OFF_C2W + i];
    }
}

// ---------------- encoder stage 1: T1 = relu(LN(x@w1+b1)), MFMA + fused LN ----------------
__global__ __launch_bounds__(128) void enc1_k(const unsigned short* __restrict__ canon,
                                              const unsigned short* __restrict__ w1t,
                                              unsigned short* __restrict__ T1) {
    const unsigned short* x = canon + OFF_X;
    __shared__ unsigned short As[128 * 72];
    __shared__ unsigned short Bs[64 * 72];
    int tid = threadIdx.x, wave = tid >> 6, lane = tid & 63;
    int q = lane >> 4, l = lane & 15;
    int row0 = blockIdx.x * 128;
    f32x4 acc[4][4];
#pragma unroll
    for (int a = 0; a < 4; ++a)
#pragma unroll
        for (int b = 0; b < 4; ++b) acc[a][b] = (f32x4){0.f, 0.f, 0.f, 0.f};
    for (int kb = 0; kb < IN_F; kb += 64) {
#pragma unroll
        for (int it = 0; it < 8; ++it) {
            int cid = it * 128 + tid;
            int r = cid >> 3, kc = cid & 7;
            int gr = row0 + r;
            uint4 v = make_uint4(0, 0, 0, 0);
            if (gr < N_NODES) v = *(const uint4*)(x + (size_t)gr * IN_F + kb + kc * 8);
            *(uint4*)&As[r * 72 + kc * 8] = v;
        }
#pragma unroll
        for (int it = 0; it < 4; ++it) {
            int cid = it * 128 + tid;
            int r = cid >> 3, kc = cid & 7;
            uint4 w = *(const uint4*)(w1t + (size_t)r * IN_F + kb + kc * 8);
            *(uint4*)&Bs[r * 72 + kc * 8] = w;
        }
        __syncthreads();
#pragma unroll
        for (int ks = 0; ks < 64; ks += 32) {
            bf16x8 af[4], bfr[4];
#pragma unroll
            for (int mt = 0; mt < 4; ++mt)
                af[mt] = *(const bf16x8*)&As[(wave * 64 + mt * 16 + l) * 72 + ks + q * 8];
#pragma unroll
            for (int nt = 0; nt < 4; ++nt)
                bfr[nt] = *(const bf16x8*)&Bs[(nt * 16 + l) * 72 + ks + q * 8];
#pragma unroll
            for (int mt = 0; mt < 4; ++mt)
#pragma unroll
                for (int nt = 0; nt < 4; ++nt)
                    acc[mt][nt] = __builtin_amdgcn_mfma_f32_16x16x32_bf16(
                        af[mt], bfr[nt], acc[mt][nt], 0, 0, 0);
        }
        __syncthreads();
    }
    float b1c[4], gc[4], bec[4];
#pragma unroll
    for (int nt = 0; nt < 4; ++nt) {
        int c = nt * 16 + l;
        b1c[nt] = bf2f(canon[OFF_EB1 + c]);
        gc[nt]  = bf2f(canon[OFF_EG + c]);
        bec[nt] = bf2f(canon[OFF_EBE + c]);
    }
#pragma unroll
    for (int mt = 0; mt < 4; ++mt) {
#pragma unroll
        for (int r = 0; r < 4; ++r) {
            int grow = row0 + wave * 64 + mt * 16 + q * 4 + r;
            float v0 = acc[mt][0][r] + b1c[0];
            float v1 = acc[mt][1][r] + b1c[1];
            float v2 = acc[mt][2][r] + b1c[2];
            float v3 = acc[mt][3][r] + b1c[3];
            float s = v0 + v1 + v2 + v3;
#pragma unroll
            for (int off = 1; off < 16; off <<= 1) s += __shfl_xor(s, off);
            float mean = s * (1.0f / 64.0f);
            float d0 = v0 - mean, d1 = v1 - mean, d2 = v2 - mean, d3 = v3 - mean;
            float vs = d0 * d0 + d1 * d1 + d2 * d2 + d3 * d3;
#pragma unroll
            for (int off = 1; off < 16; off <<= 1) vs += __shfl_xor(vs, off);
            float rstd = rsqrtf(vs * (1.0f / 64.0f) + LNEPS);
            if (grow < N_NODES) {
                unsigned short* trow = T1 + (size_t)grow * HIDF;
                float o0 = gc[0] * d0 * rstd + bec[0]; o0 = fmaxf(o0, 0.f);
                float o1 = gc[1] * d1 * rstd + bec[1]; o1 = fmaxf(o1, 0.f);
                float o2 = gc[2] * d2 * rstd + bec[2]; o2 = fmaxf(o2, 0.f);
                float o3 = gc[3] * d3 * rstd + bec[3]; o3 = fmaxf(o3, 0.f);
                trow[l] = f2bf(o0); trow[16 + l] = f2bf(o1);
                trow[32 + l] = f2bf(o2); trow[48 + l] = f2bf(o3);
            }
        }
    }
}

// ---------------- encoder stage 2: h0 = T1 @ w2 + b2 ----------------
__global__ __launch_bounds__(128) void enc2_k(const unsigned short* __restrict__ canon,
                                              const unsigned short* __restrict__ T1,
                                              const unsigned short* __restrict__ w2t,
                                              unsigned short* __restrict__ h0) {
    __shared__ unsigned short As[128 * 72];
    __shared__ unsigned short Bs[64 * 72];
    int tid = threadIdx.x, wave = tid >> 6, lane = tid & 63;
    int q = lane >> 4, l = lane & 15;
    int row0 = blockIdx.x * 128;
    f32x4 acc[4][4];
#pragma unroll
    for (int a = 0; a < 4; ++a)
#pragma unroll
        for (int b = 0; b < 4; ++b) acc[a][b] = (f32x4){0.f, 0.f, 0.f, 0.f};
#pragma unroll
    for (int it = 0; it < 8; ++it) {
        int cid = it * 128 + tid;
        int r = cid >> 3, kc = cid & 7;
        int gr = row0 + r;
        uint4 v = make_uint4(0, 0, 0, 0);
        if (gr < N_NODES) v = *(const uint4*)(T1 + (size_t)gr * HIDF + kc * 8);
        *(uint4*)&As[r * 72 + kc * 8] = v;
    }
#pragma unroll
    for (int it = 0; it < 4; ++it) {
        int cid = it * 128 + tid;
        int r = cid >> 3, kc = cid & 7;
        uint4 w = *(const uint4*)(w2t + (size_t)r * HIDF + kc * 8);
        *(uint4*)&Bs[r * 72 + kc * 8] = w;
    }
    __syncthreads();
#pragma unroll
    for (int ks = 0; ks < 64; ks += 32) {
        bf16x8 af[4], bfr[4];
#pragma unroll
        for (int mt = 0; mt < 4; ++mt)
            af[mt] = *(const bf16x8*)&As[(wave * 64 + mt * 16 + l) * 72 + ks + q * 8];
#pragma unroll
        for (int nt = 0; nt < 4; ++nt)
            bfr[nt] = *(const bf16x8*)&Bs[(nt * 16 + l) * 72 + ks + q * 8];
#pragma unroll
        for (int mt = 0; mt < 4; ++mt)
#pragma unroll
            for (int nt = 0; nt < 4; ++nt)
                acc[mt][nt] = __builtin_amdgcn_mfma_f32_16x16x32_bf16(
                    af[mt], bfr[nt], acc[mt][nt], 0, 0, 0);
    }
    float b2c[4];
#pragma unroll
    for (int nt = 0; nt < 4; ++nt) b2c[nt] = bf2f(canon[OFF_EB2 + nt * 16 + l]);
#pragma unroll
    for (int mt = 0; mt < 4; ++mt) {
#pragma unroll
        for (int r = 0; r < 4; ++r) {
            int grow = row0 + wave * 64 + mt * 16 + q * 4 + r;
            if (grow < N_NODES) {
                unsigned short* hrow = h0 + (size_t)grow * HIDF;
#pragma unroll
                for (int nt = 0; nt < 4; ++nt)
                    hrow[nt * 16 + l] = f2bf(acc[mt][nt][r] + b2c[nt]);
            }
        }
    }
}

// ---------------- CSR build ----------------
__global__ void deg_init_k(int* __restrict__ deg) {
    int i = blockIdx.x * 256 + threadIdx.x;
    if (i < N_NODES) deg[i] = 1;
}
__global__ void deg_count_k(const int* __restrict__ dstI, int* __restrict__ deg) {
    int i = blockIdx.x * 256 + threadIdx.x;
    if (i < E_EDGES) atomicAdd(&deg[dstI[i]], 1);
}
__global__ __launch_bounds__(256) void scan1_k(const int* __restrict__ deg, int* __restrict__ excl,
                                               int* __restrict__ bsums) {
    int tid = threadIdx.x, lane = tid & 63, wv = tid >> 6;
    int gid = blockIdx.x * 256 + tid;
    int v = (gid < N_NODES) ? deg[gid] : 0;
    int inc = v;
#pragma unroll
    for (int off = 1; off < 64; off <<= 1) { int t = __shfl_up(inc, off); if (lane >= off) inc += t; }
    __shared__ int wsum[4];
    if (lane == 63) wsum[wv] = inc;
    __syncthreads();
    int wo = 0;
    for (int w = 0; w < wv; ++w) wo += wsum[w];
    int incl = inc + wo;
    if (gid < N_NODES) excl[gid] = incl - v;
    if (tid == 255) bsums[blockIdx.x] = incl;
}
__global__ __launch_bounds__(256) void scan2_k(const int* __restrict__ bsums, int* __restrict__ boff,
                                               int* __restrict__ totalp) {
    int tid = threadIdx.x, lane = tid & 63, wv = tid >> 6;
    int v = (tid < NB256) ? bsums[tid] : 0;
    int inc = v;
#pragma unroll
    for (int off = 1; off < 64; off <<= 1) { int t = __shfl_up(inc, off); if (lane >= off) inc += t; }
    __shared__ int wsum[4];
    if (lane == 63) wsum[wv] = inc;
    __syncthreads();
    int wo = 0;
    for (int w = 0; w < wv; ++w) wo += wsum[w];
    int incl = inc + wo;
    if (tid < NB256) boff[tid] = incl - v;
    if (tid == 255) *totalp = incl;
}
__global__ void scan3_k(const int* __restrict__ excl, const int* __restrict__ boff,
                        int* __restrict__ rowp, int* __restrict__ cursor) {
    int i = blockIdx.x * 256 + threadIdx.x;
    if (i < N_NODES) { int r = excl[i] + boff[i >> 8]; rowp[i] = r; cursor[i] = r; }
}
__global__ void fill_k(const int* __restrict__ srcI, const int* __restrict__ dstI,
                       int* __restrict__ cursor, int* __restrict__ colx) {
    int i = blockIdx.x * 256 + threadIdx.x;
    if (i >= E_EDGES + N_NODES) return;
    int s, d;
    if (i < E_EDGES) { s = srcI[i]; d = dstI[i]; } else { s = i - E_EDGES; d = s; }
    int slot = atomicAdd(&cursor[d], 1);
    colx[slot] = s;
}

// ---------------- MFMA matmul + fused attention logits ----------------
__global__ __launch_bounds__(256) void mfma_mm_k(
    const unsigned short* __restrict__ A, const unsigned short* __restrict__ Wt,
    unsigned short* __restrict__ C, int M, int K,
    const unsigned short* __restrict__ aSv, const unsigned short* __restrict__ aDv,
    float* __restrict__ alS, float* __restrict__ alD) {
    __shared__ unsigned short smem[128 * 72 * 2];   // As | Bs; reused as C-tile (128x136)
    unsigned short* As = smem;
    unsigned short* Bs = smem + 128 * 72;
    int tid = threadIdx.x;
    int wave = tid >> 6, lane = tid & 63;
    int wm = wave >> 1, wn = wave & 1;
    int row0 = blockIdx.y * 128, col0 = blockIdx.x * 128;
    int q = lane >> 4, l = lane & 15;
    f32x4 acc[4][4];
#pragma unroll
    for (int a = 0; a < 4; ++a)
#pragma unroll
        for (int b = 0; b < 4; ++b) acc[a][b] = (f32x4){0.f, 0.f, 0.f, 0.f};
    for (int kb = 0; kb < K; kb += 64) {
#pragma unroll
        for (int it = 0; it < 4; ++it) {
            int cid = it * 256 + tid;
            int r = cid >> 3, kc = cid & 7;
            int gr = row0 + r;
            uint4 v = make_uint4(0, 0, 0, 0);
            if (gr < M) v = *(const uint4*)(A + (size_t)gr * K + kb + kc * 8);
            *(uint4*)&As[r * 72 + kc * 8] = v;
            int gn = col0 + r;
            uint4 w = *(const uint4*)(Wt + (size_t)gn * K + kb + kc * 8);
            *(uint4*)&Bs[r * 72 + kc * 8] = w;
        }
        __syncthreads();
#pragma unroll
        for (int ks = 0; ks < 64; ks += 32) {
            bf16x8 af[4], bfr[4];
#pragma unroll
            for (int mt = 0; mt < 4; ++mt)
                af[mt] = *(const bf16x8*)&As[(wm * 64 + mt * 16 + l) * 72 + ks + q * 8];
#pragma unroll
            for (int nt = 0; nt < 4; ++nt)
                bfr[nt] = *(const bf16x8*)&Bs[(wn * 64 + nt * 16 + l) * 72 + ks + q * 8];
#pragma unroll
            for (int mt = 0; mt < 4; ++mt)
#pragma unroll
                for (int nt = 0; nt < 4; ++nt)
                    acc[mt][nt] = __builtin_amdgcn_mfma_f32_16x16x32_bf16(
                        af[mt], bfr[nt], acc[mt][nt], 0, 0, 0);
        }
        __syncthreads();
    }
#pragma unroll
    for (int mt = 0; mt < 4; ++mt) {
        int rowb = wm * 64 + mt * 16 + q * 4;
#pragma unroll
        for (int r = 0; r < 4; ++r) {
#pragma unroll
            for (int nt = 0; nt < 4; ++nt)
                smem[(rowb + r) * 136 + wn * 64 + nt * 16 + l] = f2bf(acc[mt][nt][r]);
        }
    }
    __syncthreads();
    int row = tid >> 1, half = tid & 1;
    int grow = row0 + row;
    if (grow < M) {
        unsigned short* crow = C + (size_t)grow * D_F + col0 + half * 64;
        const unsigned short* srow = &smem[row * 136 + half * 64];
#pragma unroll
        for (int i = 0; i < 8; ++i)
            *(uint4*)(crow + i * 8) = *(const uint4*)(srow + i * 8);
        int head = (col0 >> 6) + half;
        const unsigned short* av = aSv + head * 64;
        const unsigned short* dv = aDv + head * 64;
        float ps = 0.f, pd = 0.f;
#pragma unroll
        for (int k = 0; k < 64; ++k) {
            float hv = bf2f(srow[k]);
            ps = fmaf(hv, bf2f(av[k]), ps);
            pd = fmaf(hv, bf2f(dv[k]), pd);
        }
        alS[(size_t)grow * 4 + head] = ps;
        alD[(size_t)grow * 4 + head] = pd;
    }
}

// ---------------- fused GAT aggregate: on-the-fly softmax denom + 16B/lane gather ----------------
__global__ __launch_bounds__(256) void agg_k(
    const unsigned short* __restrict__ h2, const int* __restrict__ rowp, const int* __restrict__ colx,
    const float* __restrict__ alS, const float* __restrict__ alD,
    const unsigned short* __restrict__ bias, unsigned short* __restrict__ out) {
    int tid = threadIdx.x, wave = tid >> 6, lane = tid & 63;
    int n = blockIdx.x * 4 + wave;
    if (n >= N_NODES) return;
    int start = rowp[n], end = rowp[n + 1];
    int e = lane >> 5;           // edge parity for this half-wave
    int c = lane & 31;           // 8-channel group
    int head = c >> 3;
    float adh = alD[(size_t)n * 4 + head];
    float acc[8] = {};
    float asum = 0.f;
    int j = start;
    for (; j + 7 < end; j += 8) {        // 8 edges, 4 per parity, 4 loads in flight
        int ja = j + e, jb = j + 2 + e, jc2 = j + 4 + e, jd = j + 6 + e;
        int sa = colx[ja], sb = colx[jb], sc = colx[jc2], sd = colx[jd];
        float ea = alS[(size_t)sa * 4 + head] + adh; ea = ea > 0.f ? ea : NEG * ea;
        float eb = alS[(size_t)sb * 4 + head] + adh; eb = eb > 0.f ? eb : NEG * eb;
        float ec = alS[(size_t)sc * 4 + head] + adh; ec = ec > 0.f ? ec : NEG * ec;
        float ed = alS[(size_t)sd * 4 + head] + adh; ed = ed > 0.f ? ed : NEG * ed;
        float wa = __expf(ea), wb = __expf(eb), wc = __expf(ec), wd = __expf(ed);
        uint4 ua = *(const uint4*)(h2 + (size_t)sa * D_F + c * 8);
        uint4 ub = *(const uint4*)(h2 + (size_t)sb * D_F + c * 8);
        uint4 uc = *(const uint4*)(h2 + (size_t)sc * D_F + c * 8);
        uint4 ud = *(const uint4*)(h2 + (size_t)sd * D_F + c * 8);
        asum += (wa + wb) + (wc + wd);
        mac8(acc, wa, ua);
        mac8(acc, wb, ub);
        mac8(acc, wc, uc);
        mac8(acc, wd, ud);
    }
    for (; j < end; j += 2) {            // pair tail + guarded single
        int j1 = j + e;
        int jc = j1 < end ? j1 : end - 1;
        int s1 = colx[jc];
        float w1 = 0.f;
        if (j1 < end) {
            float ev = alS[(size_t)s1 * 4 + head] + adh;
            ev = ev > 0.f ? ev : NEG * ev;
            w1 = __expf(ev);
        }
        uint4 u1 = *(const uint4*)(h2 + (size_t)s1 * D_F + c * 8);
        asum += w1;
        mac8(acc, w1, u1);
    }
#pragma unroll
    for (int k = 0; k < 8; ++k) acc[k] += __shfl_xor(acc[k], 32);
    asum += __shfl_xor(asum, 32);
    if (lane < 32) {
        float rh = 1.f / (asum + 1e-16f);
        uint4 bu = *(const uint4*)(bias + c * 8);
        float b[8];
        b[0] = bf2f((unsigned short)(bu.x & 0xffff)); b[1] = bf2f((unsigned short)(bu.x >> 16));
        b[2] = bf2f((unsigned short)(bu.y & 0xffff)); b[3] = bf2f((unsigned short)(bu.y >> 16));
        b[4] = bf2f((unsigned short)(bu.z & 0xffff)); b[5] = bf2f((unsigned short)(bu.z >> 16));
        b[6] = bf2f((unsigned short)(bu.w & 0xffff)); b[7] = bf2f((unsigned short)(bu.w >> 16));
        unsigned int o[4];
#pragma unroll
        for (int k = 0; k < 4; ++k) {
            float v0 = acc[2 * k] * rh + b[2 * k];
            float v1 = acc[2 * k + 1] * rh + b[2 * k + 1];
            v0 = v0 > 0.f ? v0 : __expf(v0) - 1.f;
            v1 = v1 > 0.f ? v1 : __expf(v1) - 1.f;
            o[k] = (unsigned int)f2bf(v0) | ((unsigned int)f2bf(v1) << 16);
        }
        *(uint4*)(out + (size_t)n * D_F + c * 8) = make_uint4(o[0], o[1], o[2], o[3]);
    }
}

// ---------------- pool ----------------
__global__ __launch_bounds__(256) void pool_k(const unsigned short* __restrict__ h,
                                              const int* __restrict__ batch,
                                              float* __restrict__ part, int* __restrict__ pcnt) {
    __shared__ float sums[GROUPS * D_F];
    __shared__ int cnts[GROUPS];
    int tid = threadIdx.x;
    for (int i = tid; i < GROUPS * D_F; i += 256) sums[i] = 0.f;
    if (tid < GROUPS) cnts[tid] = 0;
    __syncthreads();
    int n0 = blockIdx.x * POOL_CHUNK;
    int n1 = n0 + POOL_CHUNK; if (n1 > N_NODES) n1 = N_NODES;
    for (int n = n0; n < n1; ++n) {
        int b = batch[n];
        sums[b * D_F + tid] += bf2f(h[(size_t)n * D_F + tid]);
        if (tid == 0) cnts[b]++;
    }
    __syncthreads();
    float* po = part + (size_t)blockIdx.x * (GROUPS * D_F);
    for (int i = tid; i < GROUPS * D_F; i += 256) po[i] = sums[i];
    if (tid < GROUPS) pcnt[blockIdx.x * GROUPS + tid] = cnts[tid];
}

// ---------------- reduce ----------------
__global__ __launch_bounds__(256) void reduce_k(const float* __restrict__ part,
                                                const int* __restrict__ pcnt,
                                                float* __restrict__ gsum, int* __restrict__ gcnt) {
    int g = blockIdx.x, c = threadIdx.x;
    float s = 0.f;
    for (int b = 0; b < POOL_BLOCKS; ++b) s += part[(size_t)b * (GROUPS * D_F) + g * D_F + c];
    gsum[g * D_F + c] = s;
    if (threadIdx.x < 64) {
        int lane = threadIdx.x;
        int cn = 0;
        for (int b = lane; b < POOL_BLOCKS; b += 64) cn += pcnt[b * GROUPS + g];
#pragma unroll
        for (int off = 1; off < 64; off <<= 1) cn += __shfl_xor(cn, off);
        if (lane == 0) gcnt[g] = cn;
    }
}

// ---------------- decoder ----------------
__global__ __launch_bounds__(256) void dec_k(const float* __restrict__ gsum, const int* __restrict__ gcnt,
    const unsigned short* __restrict__ canon, const int* __restrict__ flag,
    void* __restrict__ outp) {
    const unsigned short* w1 = canon + OFF_DW1;
    const unsigned short* b1 = canon + OFF_DB1;
    const unsigned short* gam = canon + OFF_DG;
    const unsigned short* bet = canon + OFF_DBE;
    const unsigned short* w2 = canon + OFF_DW2;
    const unsigned short* b2 = canon + OFF_DB2;
    int tid = threadIdx.x, grp = blockIdx.x * 4 + (tid >> 6), lane = tid & 63;
    if (grp >= GROUPS) return;
    float inv = 1.0f / fmaxf((float)gcnt[grp], 1.0f);
    float p[4];
#pragma unroll
    for (int i = 0; i < 4; ++i) p[i] = gsum[grp * D_F + i * 64 + lane] * inv;
    float acc = bf2f(b1[lane]);
#pragma unroll
    for (int i = 0; i < 4; ++i)
        for (int k = 0; k < 64; ++k)
            acc = fmaf(__shfl(p[i], k), bf2f(w1[(i * 64 + k) * 64 + lane]), acc);
    float s = acc;
#pragma unroll
    for (int off = 32; off > 0; off >>= 1) s += __shfl_xor(s, off);
    float mean = s * (1.0f / 64.0f);
    float d = acc - mean;
    float vs = d * d;
#pragma unroll
    for (int off = 32; off > 0; off >>= 1) vs += __shfl_xor(vs, off);
    float rstd = rsqrtf(vs * (1.0f / 64.0f) + LNEPS);
    float val = bf2f(gam[lane]) * d * rstd + bf2f(bet[lane]);
    val = val > 0.f ? val : val * 0.f;
    int cl = (lane < OUT_F) ? lane : 0;
    float acc2 = 0.f;
    for (int k = 0; k < 64; ++k) {
        float wv = bf2f(w2[k * OUT_F + cl]);
        acc2 = fmaf(__shfl(val, k), wv, acc2);
    }
    if (lane < OUT_F) {
        float res = acc2 + bf2f(b2[lane]);
        if (*flag == 0) ((unsigned short*)outp)[grp * OUT_F + lane] = f2bf(res);
        else            ((float*)outp)[grp * OUT_F + lane] = res;
    }
}

extern "C" void kernel_launch(void* const* d_in, const int* in_sizes, int n_in,
                              void* d_out, int out_size, void* d_ws, size_t ws_size,
                              hipStream_t stream) {
    const int* ei    = (const int*)d_in[1];
    const int* batch = (const int*)d_in[2];

    char* p = (char*)d_ws;
    unsigned short* canon = (unsigned short*)p; p += (size_t)CANON_TOT * 2 + 16;
    unsigned short* bufA = (unsigned short*)p; p += (size_t)N_NODES * D_F * 2;
    unsigned short* bufB = (unsigned short*)p; p += (size_t)N_NODES * D_F * 2;
    unsigned short* wt0 = (unsigned short*)p; p += (size_t)64 * 256 * 2;
    unsigned short* wt1 = (unsigned short*)p; p += (size_t)256 * 256 * 2;
    unsigned short* wt2 = (unsigned short*)p; p += (size_t)256 * 256 * 2;
    unsigned short* w1t = (unsigned short*)p; p += (size_t)64 * 128 * 2;
    unsigned short* w2t = (unsigned short*)p; p += (size_t)64 * 64 * 2;
    float* alS  = (float*)p; p += (size_t)N_NODES * 4 * 4;
    float* alD  = (float*)p; p += (size_t)N_NODES * 4 * 4;
    float* part = (float*)p; p += (size_t)POOL_BLOCKS * GROUPS * D_F * 4;
    int* pcnt   = (int*)p;   p += (size_t)POOL_BLOCKS * GROUPS * 4;
    float* gsum = (float*)p; p += GROUPS * D_F * 4;
    int* gcnt   = (int*)p;   p += 16 * 4;
    int* deg    = (int*)p;   p += (size_t)N_NODES * 4;
    int* excl   = (int*)p;   p += (size_t)N_NODES * 4;
    int* bsums  = (int*)p;   p += 256 * 4;
    int* boff   = (int*)p;   p += 256 * 4;
    int* rowp   = (int*)p;   p += (size_t)(N_NODES + 4) * 4;
    int* cursor = (int*)p;   p += (size_t)N_NODES * 4;
    int* colx   = (int*)p;   p += (size_t)(E_EDGES + N_NODES) * 4;
    int* flag   = (int*)p;   p += 16;

    const int* srcI = ei;
    const int* dstI = ei + E_EDGES;

    SP sp;
    sp.q[0] = d_in[0];
    for (int t = 1; t < 25; ++t) sp.q[t] = d_in[t + 2];

    int nwb = (N_NODES + 3) / 4;
    int nb128 = (N_NODES + 127) / 128;

    flag_k<<<1, 64, 0, stream>>>((const unsigned short*)d_in[5], flag);
    convert_k<<<(CANON_TOT + 255) / 256, 256, 0, stream>>>(sp, flag, canon);
    wt_k<<<256, 256, 0, stream>>>(canon, wt0, wt1, wt2, w1t, w2t);

    enc1_k<<<nb128, 128, 0, stream>>>(canon, w1t, bufB);
    enc2_k<<<nb128, 128, 0, stream>>>(canon, bufB, w2t, bufA);

    deg_init_k<<<NB256, 256, 0, stream>>>(deg);
    deg_count_k<<<(E_EDGES + 255) / 256, 256, 0, stream>>>(dstI, deg);
    scan1_k<<<NB256, 256, 0, stream>>>(deg, excl, bsums);
    scan2_k<<<1, 256, 0, stream>>>(bsums, boff, rowp + N_NODES);
    scan3_k<<<NB256, 256, 0, stream>>>(excl, boff, rowp, cursor);
    fill_k<<<(E_EDGES + N_NODES + 255) / 256, 256, 0, stream>>>(srcI, dstI, cursor, colx);

    dim3 mmg(2, nb128);
    mfma_mm_k<<<mmg, 256, 0, stream>>>(bufA, wt0, bufB, N_NODES, HIDF,
                                       canon + OFF_C0AS, canon + OFF_C0AD, alS, alD);
    agg_k<<<nwb, 256, 0, stream>>>(bufB, rowp, colx, alS, alD, canon + OFF_C0B, bufA);

    mfma_mm_k<<<mmg, 256, 0, stream>>>(bufA, wt1, bufB, N_NODES, D_F,
                                       canon + OFF_C1AS, canon + OFF_C1AD, alS, alD);
    agg_k<<<nwb, 256, 0, stream>>>(bufB, rowp, colx, alS, alD, canon + OFF_C1B, bufA);

    mfma_mm_k<<<mmg, 256, 0, stream>>>(bufA, wt2, bufB, N_NODES, D_F,
                                       canon + OFF_C2AS, canon + OFF_C2AD, alS, alD);
    agg_k<<<nwb, 256, 0, stream>>>(bufB, rowp, colx, alS, alD, canon + OFF_C2B, bufA);

    pool_k<<<POOL_BLOCKS, 256, 0, stream>>>(bufA, batch, part, pcnt);
    reduce_k<<<GROUPS, 256, 0, stream>>>(part, pcnt, gsum, gcnt);
    dec_k<<<2, 256, 0, stream>>>(gsum, gcnt, canon, flag, d_out);
}

// Round 10
// 594.263 us; speedup vs baseline: 1.1828x; 1.0635x over previous
//
#include <hip/hip_runtime.h>
#include <hip/hip_bf16.h>

#define N_NODES 50000
#define E_EDGES 800000
#define IN_F 128
#define HIDF 64
#define HEADS 4
#define OUT_F 40
#define GROUPS 8
#define D_F 256
#define NEG 0.2f
#define LNEPS 1e-5f
#define POOL_CHUNK 128
#define POOL_BLOCKS ((N_NODES + POOL_CHUNK - 1) / POOL_CHUNK)   // 391
#define NB256 ((N_NODES + 255) / 256)                            // 196

// canonical bf16 parameter buffer: element offsets
#define OFF_X    0
#define OFF_EW1  6400000
#define OFF_EB1  6408192
#define OFF_EG   6408256
#define OFF_EBE  6408320
#define OFF_EW2  6408384
#define OFF_EB2  6412480
#define OFF_C0W  6412544
#define OFF_C0AS 6428928
#define OFF_C0AD 6429184
#define OFF_C0B  6429440
#define OFF_C1W  6429696
#define OFF_C1AS 6495232
#define OFF_C1AD 6495488
#define OFF_C1B  6495744
#define OFF_C2W  6496000
#define OFF_C2AS 6561536
#define OFF_C2AD 6561792
#define OFF_C2B  6562048
#define OFF_DW1  6562304
#define OFF_DB1  6578688
#define OFF_DG   6578752
#define OFF_DBE  6578816
#define OFF_DW2  6578880
#define OFF_DB2  6581440
#define CANON_TOT 6581480

__device__ __constant__ int c_off[26] = {
    OFF_X, OFF_EW1, OFF_EB1, OFF_EG, OFF_EBE, OFF_EW2, OFF_EB2,
    OFF_C0W, OFF_C0AS, OFF_C0AD, OFF_C0B,
    OFF_C1W, OFF_C1AS, OFF_C1AD, OFF_C1B,
    OFF_C2W, OFF_C2AS, OFF_C2AD, OFF_C2B,
    OFF_DW1, OFF_DB1, OFF_DG, OFF_DBE, OFF_DW2, OFF_DB2, CANON_TOT};

typedef __attribute__((ext_vector_type(8))) short bf16x8;
typedef __attribute__((ext_vector_type(4))) float f32x4;

__device__ __forceinline__ float bf2f(unsigned short u) {
    union { unsigned int i; float f; } v; v.i = ((unsigned int)u) << 16; return v.f;
}
__device__ __forceinline__ unsigned short f2bf(float f) {
    union { float f; unsigned int i; } v; v.f = f;
    unsigned int r = v.i + 0x7FFF + ((v.i >> 16) & 1);   // RNE
    return (unsigned short)(r >> 16);
}
__device__ __forceinline__ void mac8(float* acc, float w, uint4 u) {
    acc[0] = fmaf(w, bf2f((unsigned short)(u.x & 0xffff)), acc[0]);
    acc[1] = fmaf(w, bf2f((unsigned short)(u.x >> 16)),    acc[1]);
    acc[2] = fmaf(w, bf2f((unsigned short)(u.y & 0xffff)), acc[2]);
    acc[3] = fmaf(w, bf2f((unsigned short)(u.y >> 16)),    acc[3]);
    acc[4] = fmaf(w, bf2f((unsigned short)(u.z & 0xffff)), acc[4]);
    acc[5] = fmaf(w, bf2f((unsigned short)(u.z >> 16)),    acc[5]);
    acc[6] = fmaf(w, bf2f((unsigned short)(u.w & 0xffff)), acc[6]);
    acc[7] = fmaf(w, bf2f((unsigned short)(u.w >> 16)),    acc[7]);
}

// ---------- dtype flag ----------
__global__ void flag_k(const unsigned short* __restrict__ encg, int* __restrict__ flag) {
    if (threadIdx.x == 0 && blockIdx.x == 0) {
        unsigned short a = encg[0], b = encg[1];
        int f = 0;
        if (a == 0x0000 && b == 0x3F80) f = 1;
        *flag = f;
    }
}

// ---------- canonicalize (fast path for x) ----------
struct SP { const void* q[25]; };
__global__ __launch_bounds__(256) void convert_k(SP sp, const int* __restrict__ flag,
                                                 unsigned short* __restrict__ canon) {
    int i = blockIdx.x * 256 + threadIdx.x;
    if (i >= CANON_TOT) return;
    int fl = *flag;
    if (i < OFF_EW1) {
        canon[i] = fl == 0 ? ((const unsigned short*)sp.q[0])[i]
                           : f2bf(((const float*)sp.q[0])[i]);
        return;
    }
    int t = 1;
    while (i >= c_off[t + 1]) ++t;
    int j = i - c_off[t];
    const void* s = sp.q[t];
    canon[i] = fl == 0 ? ((const unsigned short*)s)[j] : f2bf(((const float*)s)[j]);
}

// ---------- weight transposes + layer-0 logit projection P0 = W0·a (64x8) ----------
__global__ void wt_k(const unsigned short* __restrict__ canon,
                     unsigned short* __restrict__ wt0, unsigned short* __restrict__ wt1,
                     unsigned short* __restrict__ wt2, unsigned short* __restrict__ w1t,
                     unsigned short* __restrict__ w2t, unsigned short* __restrict__ p0) {
    int i = blockIdx.x * 256 + threadIdx.x;   // 65536 threads
    if (i < 8192) {
        int k = i >> 6, n = i & 63;
        w1t[n * 128 + k] = canon[OFF_EW1 + k * 64 + n];
    }
    if (i < 4096) {
        int k = i >> 6, n = i & 63;
        w2t[n * 64 + k] = canon[OFF_EW2 + k * 64 + n];
    }
    if (i < 16384) {
        int k = i >> 8, n = i & 255;
        wt0[n * 64 + k] = canon[OFF_C0W + i];
    }
    if (i < 65536) {
        int k = i >> 8, n = i & 255;
        wt1[n * 256 + k] = canon[OFF_C1W + i];
        wt2[n * 256 + k] = canon[OFF_C2W + i];
    }
    if (i < 512) {   // P0[k][out], out = sd*4+h: p0[k*8+out] = sum_c W0[k,h*64+c]*a_{sd}[h,c]
        int out = i & 7, k = i >> 3;
        int h = out & 3, sd = out >> 2;
        int abase = (sd == 0 ? OFF_C0AS : OFF_C0AD) + h * 64;
        int wbase = OFF_C0W + k * 256 + h * 64;
        float s = 0.f;
        for (int c = 0; c < 64; ++c)
            s = fmaf(bf2f(canon[wbase + c]), bf2f(canon[abase + c]), s);
        p0[k * 8 + out] = f2bf(s);
    }
}

// ---------------- encoder stage 1: T1 = relu(LN(x@w1+b1)), MFMA + fused LN ----------------
__global__ __launch_bounds__(128) void enc1_k(const unsigned short* __restrict__ canon,
                                              const unsigned short* __restrict__ w1t,
                                              unsigned short* __restrict__ T1) {
    const unsigned short* x = canon + OFF_X;
    __shared__ unsigned short As[128 * 72];
    __shared__ unsigned short Bs[64 * 72];
    int tid = threadIdx.x, wave = tid >> 6, lane = tid & 63;
    int q = lane >> 4, l = lane & 15;
    int row0 = blockIdx.x * 128;
    f32x4 acc[4][4];
#pragma unroll
    for (int a = 0; a < 4; ++a)
#pragma unroll
        for (int b = 0; b < 4; ++b) acc[a][b] = (f32x4){0.f, 0.f, 0.f, 0.f};
    for (int kb = 0; kb < IN_F; kb += 64) {
#pragma unroll
        for (int it = 0; it < 8; ++it) {
            int cid = it * 128 + tid;
            int r = cid >> 3, kc = cid & 7;
            int gr = row0 + r;
            uint4 v = make_uint4(0, 0, 0, 0);
            if (gr < N_NODES) v = *(const uint4*)(x + (size_t)gr * IN_F + kb + kc * 8);
            *(uint4*)&As[r * 72 + kc * 8] = v;
        }
#pragma unroll
        for (int it = 0; it < 4; ++it) {
            int cid = it * 128 + tid;
            int r = cid >> 3, kc = cid & 7;
            uint4 w = *(const uint4*)(w1t + (size_t)r * IN_F + kb + kc * 8);
            *(uint4*)&Bs[r * 72 + kc * 8] = w;
        }
        __syncthreads();
#pragma unroll
        for (int ks = 0; ks < 64; ks += 32) {
            bf16x8 af[4], bfr[4];
#pragma unroll
            for (int mt = 0; mt < 4; ++mt)
                af[mt] = *(const bf16x8*)&As[(wave * 64 + mt * 16 + l) * 72 + ks + q * 8];
#pragma unroll
            for (int nt = 0; nt < 4; ++nt)
                bfr[nt] = *(const bf16x8*)&Bs[(nt * 16 + l) * 72 + ks + q * 8];
#pragma unroll
            for (int mt = 0; mt < 4; ++mt)
#pragma unroll
                for (int nt = 0; nt < 4; ++nt)
                    acc[mt][nt] = __builtin_amdgcn_mfma_f32_16x16x32_bf16(
                        af[mt], bfr[nt], acc[mt][nt], 0, 0, 0);
        }
        __syncthreads();
    }
    float b1c[4], gc[4], bec[4];
#pragma unroll
    for (int nt = 0; nt < 4; ++nt) {
        int c = nt * 16 + l;
        b1c[nt] = bf2f(canon[OFF_EB1 + c]);
        gc[nt]  = bf2f(canon[OFF_EG + c]);
        bec[nt] = bf2f(canon[OFF_EBE + c]);
    }
#pragma unroll
    for (int mt = 0; mt < 4; ++mt) {
#pragma unroll
        for (int r = 0; r < 4; ++r) {
            int grow = row0 + wave * 64 + mt * 16 + q * 4 + r;
            float v0 = acc[mt][0][r] + b1c[0];
            float v1 = acc[mt][1][r] + b1c[1];
            float v2 = acc[mt][2][r] + b1c[2];
            float v3 = acc[mt][3][r] + b1c[3];
            float s = v0 + v1 + v2 + v3;
#pragma unroll
            for (int off = 1; off < 16; off <<= 1) s += __shfl_xor(s, off);
            float mean = s * (1.0f / 64.0f);
            float d0 = v0 - mean, d1 = v1 - mean, d2 = v2 - mean, d3 = v3 - mean;
            float vs = d0 * d0 + d1 * d1 + d2 * d2 + d3 * d3;
#pragma unroll
            for (int off = 1; off < 16; off <<= 1) vs += __shfl_xor(vs, off);
            float rstd = rsqrtf(vs * (1.0f / 64.0f) + LNEPS);
            if (grow < N_NODES) {
                unsigned short* trow = T1 + (size_t)grow * HIDF;
                float o0 = gc[0] * d0 * rstd + bec[0]; o0 = fmaxf(o0, 0.f);
                float o1 = gc[1] * d1 * rstd + bec[1]; o1 = fmaxf(o1, 0.f);
                float o2 = gc[2] * d2 * rstd + bec[2]; o2 = fmaxf(o2, 0.f);
                float o3 = gc[3] * d3 * rstd + bec[3]; o3 = fmaxf(o3, 0.f);
                trow[l] = f2bf(o0); trow[16 + l] = f2bf(o1);
                trow[32 + l] = f2bf(o2); trow[48 + l] = f2bf(o3);
            }
        }
    }
}

// ---------------- encoder stage 2: h0 = T1 @ w2 + b2 ----------------
__global__ __launch_bounds__(128) void enc2_k(const unsigned short* __restrict__ canon,
                                              const unsigned short* __restrict__ T1,
                                              const unsigned short* __restrict__ w2t,
                                              unsigned short* __restrict__ h0) {
    __shared__ unsigned short As[128 * 72];
    __shared__ unsigned short Bs[64 * 72];
    int tid = threadIdx.x, wave = tid >> 6, lane = tid & 63;
    int q = lane >> 4, l = lane & 15;
    int row0 = blockIdx.x * 128;
    f32x4 acc[4][4];
#pragma unroll
    for (int a = 0; a < 4; ++a)
#pragma unroll
        for (int b = 0; b < 4; ++b) acc[a][b] = (f32x4){0.f, 0.f, 0.f, 0.f};
#pragma unroll
    for (int it = 0; it < 8; ++it) {
        int cid = it * 128 + tid;
        int r = cid >> 3, kc = cid & 7;
        int gr = row0 + r;
        uint4 v = make_uint4(0, 0, 0, 0);
        if (gr < N_NODES) v = *(const uint4*)(T1 + (size_t)gr * HIDF + kc * 8);
        *(uint4*)&As[r * 72 + kc * 8] = v;
    }
#pragma unroll
    for (int it = 0; it < 4; ++it) {
        int cid = it * 128 + tid;
        int r = cid >> 3, kc = cid & 7;
        uint4 w = *(const uint4*)(w2t + (size_t)r * HIDF + kc * 8);
        *(uint4*)&Bs[r * 72 + kc * 8] = w;
    }
    __syncthreads();
#pragma unroll
    for (int ks = 0; ks < 64; ks += 32) {
        bf16x8 af[4], bfr[4];
#pragma unroll
        for (int mt = 0; mt < 4; ++mt)
            af[mt] = *(const bf16x8*)&As[(wave * 64 + mt * 16 + l) * 72 + ks + q * 8];
#pragma unroll
        for (int nt = 0; nt < 4; ++nt)
            bfr[nt] = *(const bf16x8*)&Bs[(nt * 16 + l) * 72 + ks + q * 8];
#pragma unroll
        for (int mt = 0; mt < 4; ++mt)
#pragma unroll
            for (int nt = 0; nt < 4; ++nt)
                acc[mt][nt] = __builtin_amdgcn_mfma_f32_16x16x32_bf16(
                    af[mt], bfr[nt], acc[mt][nt], 0, 0, 0);
    }
    float b2c[4];
#pragma unroll
    for (int nt = 0; nt < 4; ++nt) b2c[nt] = bf2f(canon[OFF_EB2 + nt * 16 + l]);
#pragma unroll
    for (int mt = 0; mt < 4; ++mt) {
#pragma unroll
        for (int r = 0; r < 4; ++r) {
            int grow = row0 + wave * 64 + mt * 16 + q * 4 + r;
            if (grow < N_NODES) {
                unsigned short* hrow = h0 + (size_t)grow * HIDF;
#pragma unroll
                for (int nt = 0; nt < 4; ++nt)
                    hrow[nt * 16 + l] = f2bf(acc[mt][nt][r] + b2c[nt]);
            }
        }
    }
}

// ---------------- CSR build ----------------
__global__ void deg_init_k(int* __restrict__ deg) {
    int i = blockIdx.x * 256 + threadIdx.x;
    if (i < N_NODES) deg[i] = 1;
}
__global__ void deg_count_k(const int* __restrict__ dstI, int* __restrict__ deg) {
    int i = blockIdx.x * 256 + threadIdx.x;
    if (i < E_EDGES) atomicAdd(&deg[dstI[i]], 1);
}
__global__ __launch_bounds__(256) void scan1_k(const int* __restrict__ deg, int* __restrict__ excl,
                                               int* __restrict__ bsums) {
    int tid = threadIdx.x, lane = tid & 63, wv = tid >> 6;
    int gid = blockIdx.x * 256 + tid;
    int v = (gid < N_NODES) ? deg[gid] : 0;
    int inc = v;
#pragma unroll
    for (int off = 1; off < 64; off <<= 1) { int t = __shfl_up(inc, off); if (lane >= off) inc += t; }
    __shared__ int wsum[4];
    if (lane == 63) wsum[wv] = inc;
    __syncthreads();
    int wo = 0;
    for (int w = 0; w < wv; ++w) wo += wsum[w];
    int incl = inc + wo;
    if (gid < N_NODES) excl[gid] = incl - v;
    if (tid == 255) bsums[blockIdx.x] = incl;
}
__global__ __launch_bounds__(256) void scan2_k(const int* __restrict__ bsums, int* __restrict__ boff,
                                               int* __restrict__ totalp) {
    int tid = threadIdx.x, lane = tid & 63, wv = tid >> 6;
    int v = (tid < NB256) ? bsums[tid] : 0;
    int inc = v;
#pragma unroll
    for (int off = 1; off < 64; off <<= 1) { int t = __shfl_up(inc, off); if (lane >= off) inc += t; }
    __shared__ int wsum[4];
    if (lane == 63) wsum[wv] = inc;
    __syncthreads();
    int wo = 0;
    for (int w = 0; w < wv; ++w) wo += wsum[w];
    int incl = inc + wo;
    if (tid < NB256) boff[tid] = incl - v;
    if (tid == 255) *totalp = incl;
}
__global__ void scan3_k(const int* __restrict__ excl, const int* __restrict__ boff,
                        int* __restrict__ rowp, int* __restrict__ cursor) {
    int i = blockIdx.x * 256 + threadIdx.x;
    if (i < N_NODES) { int r = excl[i] + boff[i >> 8]; rowp[i] = r; cursor[i] = r; }
}
__global__ void fill_k(const int* __restrict__ srcI, const int* __restrict__ dstI,
                       int* __restrict__ cursor, int* __restrict__ colx) {
    int i = blockIdx.x * 256 + threadIdx.x;
    if (i >= E_EDGES + N_NODES) return;
    int s, d;
    if (i < E_EDGES) { s = srcI[i]; d = dstI[i]; } else { s = i - E_EDGES; d = s; }
    int slot = atomicAdd(&cursor[d], 1);
    colx[slot] = s;
}

// ---------------- layer-0 logits: al[n,out] = h0[n,:] · P0[:,out] ----------------
__global__ __launch_bounds__(256) void att0_k(const unsigned short* __restrict__ h0,
                                              const unsigned short* __restrict__ p0,
                                              float* __restrict__ alS, float* __restrict__ alD) {
    __shared__ float p0s[512];
    int tid = threadIdx.x;
    p0s[tid] = bf2f(p0[tid]);
    p0s[tid + 256] = bf2f(p0[tid + 256]);
    __syncthreads();
    int gid = blockIdx.x * 256 + tid;
    if (gid >= N_NODES * 8) return;
    int n = gid >> 3, out = gid & 7;
    const unsigned short* hr = h0 + (size_t)n * HIDF;
    float s = 0.f;
#pragma unroll
    for (int i = 0; i < 8; ++i) {
        uint4 u = *(const uint4*)(hr + i * 8);
        const float* pp = &p0s[i * 64 + out];   // p0s[k*8+out], k = i*8+j
        s = fmaf(bf2f((unsigned short)(u.x & 0xffff)), pp[0],  s);
        s = fmaf(bf2f((unsigned short)(u.x >> 16)),    pp[8],  s);
        s = fmaf(bf2f((unsigned short)(u.y & 0xffff)), pp[16], s);
        s = fmaf(bf2f((unsigned short)(u.y >> 16)),    pp[24], s);
        s = fmaf(bf2f((unsigned short)(u.z & 0xffff)), pp[32], s);
        s = fmaf(bf2f((unsigned short)(u.z >> 16)),    pp[40], s);
        s = fmaf(bf2f((unsigned short)(u.w & 0xffff)), pp[48], s);
        s = fmaf(bf2f((unsigned short)(u.w >> 16)),    pp[56], s);
    }
    int h = out & 3;
    if ((out >> 2) == 0) alS[(size_t)n * 4 + h] = s;
    else                 alD[(size_t)n * 4 + h] = s;
}

// ---------------- layer-0 aggregate in 64-dim h0 space: z0[n] = softmax-agg(h0[src]) ----------------
__global__ __launch_bounds__(256) void agg0_k(
    const unsigned short* __restrict__ h0, const int* __restrict__ rowp, const int* __restrict__ colx,
    const float* __restrict__ alS, const float* __restrict__ alD,
    unsigned short* __restrict__ z0) {
    int tid = threadIdx.x, wave = tid >> 6, lane = tid & 63;
    int n = blockIdx.x * 4 + wave;
    if (n >= N_NODES) return;
    int start = rowp[n], end = rowp[n + 1];
    int e = lane >> 5;            // edge parity
    int c = lane & 31;            // 2-channel group: channels 2c, 2c+1
    int head = c >> 3;
    float adh = alD[(size_t)n * 4 + head];
    float a0 = 0.f, a1 = 0.f, asum = 0.f;
    int j = start;
    for (; j + 7 < end; j += 8) {
        int ja = j + e, jb = j + 2 + e, jc2 = j + 4 + e, jd = j + 6 + e;
        int sa = colx[ja], sb = colx[jb], sc = colx[jc2], sd = colx[jd];
        float ea = alS[(size_t)sa * 4 + head] + adh; ea = ea > 0.f ? ea : NEG * ea;
        float eb = alS[(size_t)sb * 4 + head] + adh; eb = eb > 0.f ? eb : NEG * eb;
        float ec = alS[(size_t)sc * 4 + head] + adh; ec = ec > 0.f ? ec : NEG * ec;
        float ed = alS[(size_t)sd * 4 + head] + adh; ed = ed > 0.f ? ed : NEG * ed;
        float wa = __expf(ea), wb = __expf(eb), wc = __expf(ec), wd = __expf(ed);
        unsigned int ua = *(const unsigned int*)(h0 + (size_t)sa * HIDF + c * 2);
        unsigned int ub = *(const unsigned int*)(h0 + (size_t)sb * HIDF + c * 2);
        unsigned int uc = *(const unsigned int*)(h0 + (size_t)sc * HIDF + c * 2);
        unsigned int ud = *(const unsigned int*)(h0 + (size_t)sd * HIDF + c * 2);
        asum += (wa + wb) + (wc + wd);
        a0 = fmaf(wa, bf2f((unsigned short)(ua & 0xffff)), a0);
        a1 = fmaf(wa, bf2f((unsigned short)(ua >> 16)),    a1);
        a0 = fmaf(wb, bf2f((unsigned short)(ub & 0xffff)), a0);
        a1 = fmaf(wb, bf2f((unsigned short)(ub >> 16)),    a1);
        a0 = fmaf(wc, bf2f((unsigned short)(uc & 0xffff)), a0);
        a1 = fmaf(wc, bf2f((unsigned short)(uc >> 16)),    a1);
        a0 = fmaf(wd, bf2f((unsigned short)(ud & 0xffff)), a0);
        a1 = fmaf(wd, bf2f((unsigned short)(ud >> 16)),    a1);
    }
    for (; j < end; j += 2) {
        int j1 = j + e;
        int jc = j1 < end ? j1 : end - 1;
        int s1 = colx[jc];
        float w1 = 0.f;
        if (j1 < end) {
            float ev = alS[(size_t)s1 * 4 + head] + adh;
            ev = ev > 0.f ? ev : NEG * ev;
            w1 = __expf(ev);
        }
        unsigned int u1 = *(const unsigned int*)(h0 + (size_t)s1 * HIDF + c * 2);
        asum += w1;
        a0 = fmaf(w1, bf2f((unsigned short)(u1 & 0xffff)), a0);
        a1 = fmaf(w1, bf2f((unsigned short)(u1 >> 16)),    a1);
    }
    a0 += __shfl_xor(a0, 32);
    a1 += __shfl_xor(a1, 32);
    asum += __shfl_xor(asum, 32);
    if (lane < 32) {
        float rh = 1.f / (asum + 1e-16f);
        unsigned int o = (unsigned int)f2bf(a0 * rh) | ((unsigned int)f2bf(a1 * rh) << 16);
        *(unsigned int*)(z0 + (size_t)n * HIDF + c * 2) = o;
    }
}

// ---------------- MFMA matmul; optional bias+ELU epilogue; optional fused logits ----------------
__global__ __launch_bounds__(256) void mfma_mm_k(
    const unsigned short* __restrict__ A, const unsigned short* __restrict__ Wt,
    unsigned short* __restrict__ C, int M, int K,
    const unsigned short* __restrict__ bias,
    const unsigned short* __restrict__ aSv, const unsigned short* __restrict__ aDv,
    float* __restrict__ alS, float* __restrict__ alD) {
    __shared__ unsigned short smem[128 * 72 * 2];   // As | Bs; reused as C-tile (128x136)
    unsigned short* As = smem;
    unsigned short* Bs = smem + 128 * 72;
    int tid = threadIdx.x;
    int wave = tid >> 6, lane = tid & 63;
    int wm = wave >> 1, wn = wave & 1;
    int row0 = blockIdx.y * 128, col0 = blockIdx.x * 128;
    int q = lane >> 4, l = lane & 15;
    f32x4 acc[4][4];
#pragma unroll
    for (int a = 0; a < 4; ++a)
#pragma unroll
        for (int b = 0; b < 4; ++b) acc[a][b] = (f32x4){0.f, 0.f, 0.f, 0.f};
    for (int kb = 0; kb < K; kb += 64) {
#pragma unroll
        for (int it = 0; it < 4; ++it) {
            int cid = it * 256 + tid;
            int r = cid >> 3, kc = cid & 7;
            int gr = row0 + r;
            uint4 v = make_uint4(0, 0, 0, 0);
            if (gr < M) v = *(const uint4*)(A + (size_t)gr * K + kb + kc * 8);
            *(uint4*)&As[r * 72 + kc * 8] = v;
            int gn = col0 + r;
            uint4 w = *(const uint4*)(Wt + (size_t)gn * K + kb + kc * 8);
            *(uint4*)&Bs[r * 72 + kc * 8] = w;
        }
        __syncthreads();
#pragma unroll
        for (int ks = 0; ks < 64; ks += 32) {
            bf16x8 af[4], bfr[4];
#pragma unroll
            for (int mt = 0; mt < 4; ++mt)
                af[mt] = *(const bf16x8*)&As[(wm * 64 + mt * 16 + l) * 72 + ks + q * 8];
#pragma unroll
            for (int nt = 0; nt < 4; ++nt)
                bfr[nt] = *(const bf16x8*)&Bs[(wn * 64 + nt * 16 + l) * 72 + ks + q * 8];
#pragma unroll
            for (int mt = 0; mt < 4; ++mt)
#pragma unroll
                for (int nt = 0; nt < 4; ++nt)
                    acc[mt][nt] = __builtin_amdgcn_mfma_f32_16x16x32_bf16(
                        af[mt], bfr[nt], acc[mt][nt], 0, 0, 0);
        }
        __syncthreads();
    }
    float bv[4] = {0.f, 0.f, 0.f, 0.f};
    bool doBias = (bias != nullptr);
    if (doBias) {
#pragma unroll
        for (int nt = 0; nt < 4; ++nt)
            bv[nt] = bf2f(bias[col0 + wn * 64 + nt * 16 + l]);
    }
#pragma unroll
    for (int mt = 0; mt < 4; ++mt) {
        int rowb = wm * 64 + mt * 16 + q * 4;
#pragma unroll
        for (int r = 0; r < 4; ++r) {
#pragma unroll
            for (int nt = 0; nt < 4; ++nt) {
                float v = acc[mt][nt][r];
                if (doBias) { v += bv[nt]; v = v > 0.f ? v : __expf(v) - 1.f; }
                smem[(rowb + r) * 136 + wn * 64 + nt * 16 + l] = f2bf(v);
            }
        }
    }
    __syncthreads();
    int row = tid >> 1, half = tid & 1;
    int grow = row0 + row;
    if (grow < M) {
        unsigned short* crow = C + (size_t)grow * D_F + col0 + half * 64;
        const unsigned short* srow = &smem[row * 136 + half * 64];
#pragma unroll
        for (int i = 0; i < 8; ++i)
            *(uint4*)(crow + i * 8) = *(const uint4*)(srow + i * 8);
        if (aSv != nullptr) {
            int head = (col0 >> 6) + half;
            const unsigned short* av = aSv + head * 64;
            const unsigned short* dv = aDv + head * 64;
            float ps = 0.f, pd = 0.f;
#pragma unroll
            for (int k = 0; k < 64; ++k) {
                float hv = bf2f(srow[k]);
                ps = fmaf(hv, bf2f(av[k]), ps);
                pd = fmaf(hv, bf2f(dv[k]), pd);
            }
            alS[(size_t)grow * 4 + head] = ps;
            alD[(size_t)grow * 4 + head] = pd;
        }
    }
}

// ---------------- fused GAT aggregate (256-dim, layers 1/2): denom on the fly + bias/ELU ----------------
__global__ __launch_bounds__(256) void agg_k(
    const unsigned short* __restrict__ h2, const int* __restrict__ rowp, const int* __restrict__ colx,
    const float* __restrict__ alS, const float* __restrict__ alD,
    const unsigned short* __restrict__ bias, unsigned short* __restrict__ out) {
    int tid = threadIdx.x, wave = tid >> 6, lane = tid & 63;
    int n = blockIdx.x * 4 + wave;
    if (n >= N_NODES) return;
    int start = rowp[n], end = rowp[n + 1];
    int e = lane >> 5;
    int c = lane & 31;
    int head = c >> 3;
    float adh = alD[(size_t)n * 4 + head];
    float acc[8] = {};
    float asum = 0.f;
    int j = start;
    for (; j + 7 < end; j += 8) {
        int ja = j + e, jb = j + 2 + e, jc2 = j + 4 + e, jd = j + 6 + e;
        int sa = colx[ja], sb = colx[jb], sc = colx[jc2], sd = colx[jd];
        float ea = alS[(size_t)sa * 4 + head] + adh; ea = ea > 0.f ? ea : NEG * ea;
        float eb = alS[(size_t)sb * 4 + head] + adh; eb = eb > 0.f ? eb : NEG * eb;
        float ec = alS[(size_t)sc * 4 + head] + adh; ec = ec > 0.f ? ec : NEG * ec;
        float ed = alS[(size_t)sd * 4 + head] + adh; ed = ed > 0.f ? ed : NEG * ed;
        float wa = __expf(ea), wb = __expf(eb), wc = __expf(ec), wd = __expf(ed);
        uint4 ua = *(const uint4*)(h2 + (size_t)sa * D_F + c * 8);
        uint4 ub = *(const uint4*)(h2 + (size_t)sb * D_F + c * 8);
        uint4 uc = *(const uint4*)(h2 + (size_t)sc * D_F + c * 8);
        uint4 ud = *(const uint4*)(h2 + (size_t)sd * D_F + c * 8);
        asum += (wa + wb) + (wc + wd);
        mac8(acc, wa, ua);
        mac8(acc, wb, ub);
        mac8(acc, wc, uc);
        mac8(acc, wd, ud);
    }
    for (; j < end; j += 2) {
        int j1 = j + e;
        int jc = j1 < end ? j1 : end - 1;
        int s1 = colx[jc];
        float w1 = 0.f;
        if (j1 < end) {
            float ev = alS[(size_t)s1 * 4 + head] + adh;
            ev = ev > 0.f ? ev : NEG * ev;
            w1 = __expf(ev);
        }
        uint4 u1 = *(const uint4*)(h2 + (size_t)s1 * D_F + c * 8);
        asum += w1;
        mac8(acc, w1, u1);
    }
#pragma unroll
    for (int k = 0; k < 8; ++k) acc[k] += __shfl_xor(acc[k], 32);
    asum += __shfl_xor(asum, 32);
    if (lane < 32) {
        float rh = 1.f / (asum + 1e-16f);
        uint4 bu = *(const uint4*)(bias + c * 8);
        float b[8];
        b[0] = bf2f((unsigned short)(bu.x & 0xffff)); b[1] = bf2f((unsigned short)(bu.x >> 16));
        b[2] = bf2f((unsigned short)(bu.y & 0xffff)); b[3] = bf2f((unsigned short)(bu.y >> 16));
        b[4] = bf2f((unsigned short)(bu.z & 0xffff)); b[5] = bf2f((unsigned short)(bu.z >> 16));
        b[6] = bf2f((unsigned short)(bu.w & 0xffff)); b[7] = bf2f((unsigned short)(bu.w >> 16));
        unsigned int o[4];
#pragma unroll
        for (int k = 0; k < 4; ++k) {
            float v0 = acc[2 * k] * rh + b[2 * k];
            float v1 = acc[2 * k + 1] * rh + b[2 * k + 1];
            v0 = v0 > 0.f ? v0 : __expf(v0) - 1.f;
            v1 = v1 > 0.f ? v1 : __expf(v1) - 1.f;
            o[k] = (unsigned int)f2bf(v0) | ((unsigned int)f2bf(v1) << 16);
        }
        *(uint4*)(out + (size_t)n * D_F + c * 8) = make_uint4(o[0], o[1], o[2], o[3]);
    }
}

// ---------------- pool ----------------
__global__ __launch_bounds__(256) void pool_k(const unsigned short* __restrict__ h,
                                              const int* __restrict__ batch,
                                              float* __restrict__ part, int* __restrict__ pcnt) {
    __shared__ float sums[GROUPS * D_F];
    __shared__ int cnts[GROUPS];
    int tid = threadIdx.x;
    for (int i = tid; i < GROUPS * D_F; i += 256) sums[i] = 0.f;
    if (tid < GROUPS) cnts[tid] = 0;
    __syncthreads();
    int n0 = blockIdx.x * POOL_CHUNK;
    int n1 = n0 + POOL_CHUNK; if (n1 > N_NODES) n1 = N_NODES;
    for (int n = n0; n < n1; ++n) {
        int b = batch[n];
        sums[b * D_F + tid] += bf2f(h[(size_t)n * D_F + tid]);
        if (tid == 0) cnts[b]++;
    }
    __syncthreads();
    float* po = part + (size_t)blockIdx.x * (GROUPS * D_F);
    for (int i = tid; i < GROUPS * D_F; i += 256) po[i] = sums[i];
    if (tid < GROUPS) pcnt[blockIdx.x * GROUPS + tid] = cnts[tid];
}

// ---------------- reduce ----------------
__global__ __launch_bounds__(256) void reduce_k(const float* __restrict__ part,
                                                const int* __restrict__ pcnt,
                                                float* __restrict__ gsum, int* __restrict__ gcnt) {
    int g = blockIdx.x, c = threadIdx.x;
    float s = 0.f;
    for (int b = 0; b < POOL_BLOCKS; ++b) s += part[(size_t)b * (GROUPS * D_F) + g * D_F + c];
    gsum[g * D_F + c] = s;
    if (threadIdx.x < 64) {
        int lane = threadIdx.x;
        int cn = 0;
        for (int b = lane; b < POOL_BLOCKS; b += 64) cn += pcnt[b * GROUPS + g];
#pragma unroll
        for (int off = 1; off < 64; off <<= 1) cn += __shfl_xor(cn, off);
        if (lane == 0) gcnt[g] = cn;
    }
}

// ---------------- decoder ----------------
__global__ __launch_bounds__(256) void dec_k(const float* __restrict__ gsum, const int* __restrict__ gcnt,
    const unsigned short* __restrict__ canon, const int* __restrict__ flag,
    void* __restrict__ outp) {
    const unsigned short* w1 = canon + OFF_DW1;
    const unsigned short* b1 = canon + OFF_DB1;
    const unsigned short* gam = canon + OFF_DG;
    const unsigned short* bet = canon + OFF_DBE;
    const unsigned short* w2 = canon + OFF_DW2;
    const unsigned short* b2 = canon + OFF_DB2;
    int tid = threadIdx.x, grp = blockIdx.x * 4 + (tid >> 6), lane = tid & 63;
    if (grp >= GROUPS) return;
    float inv = 1.0f / fmaxf((float)gcnt[grp], 1.0f);
    float p[4];
#pragma unroll
    for (int i = 0; i < 4; ++i) p[i] = gsum[grp * D_F + i * 64 + lane] * inv;
    float acc = bf2f(b1[lane]);
#pragma unroll
    for (int i = 0; i < 4; ++i)
        for (int k = 0; k < 64; ++k)
            acc = fmaf(__shfl(p[i], k), bf2f(w1[(i * 64 + k) * 64 + lane]), acc);
    float s = acc;
#pragma unroll
    for (int off = 32; off > 0; off >>= 1) s += __shfl_xor(s, off);
    float mean = s * (1.0f / 64.0f);
    float d = acc - mean;
    float vs = d * d;
#pragma unroll
    for (int off = 32; off > 0; off >>= 1) vs += __shfl_xor(vs, off);
    float rstd = rsqrtf(vs * (1.0f / 64.0f) + LNEPS);
    float val = bf2f(gam[lane]) * d * rstd + bf2f(bet[lane]);
    val = val > 0.f ? val : val * 0.f;
    int cl = (lane < OUT_F) ? lane : 0;
    float acc2 = 0.f;
    for (int k = 0; k < 64; ++k) {
        float wv = bf2f(w2[k * OUT_F + cl]);
        acc2 = fmaf(__shfl(val, k), wv, acc2);
    }
    if (lane < OUT_F) {
        float res = acc2 + bf2f(b2[lane]);
        if (*flag == 0) ((unsigned short*)outp)[grp * OUT_F + lane] = f2bf(res);
        else            ((float*)outp)[grp * OUT_F + lane] = res;
    }
}

extern "C" void kernel_launch(void* const* d_in, const int* in_sizes, int n_in,
                              void* d_out, int out_size, void* d_ws, size_t ws_size,
                              hipStream_t stream) {
    const int* ei    = (const int*)d_in[1];
    const int* batch = (const int*)d_in[2];

    char* p = (char*)d_ws;
    unsigned short* canon = (unsigned short*)p; p += (size_t)CANON_TOT * 2 + 16;
    unsigned short* bufA = (unsigned short*)p; p += (size_t)N_NODES * D_F * 2;
    unsigned short* bufB = (unsigned short*)p; p += (size_t)N_NODES * D_F * 2;
    unsigned short* zbuf = (unsigned short*)p; p += (size_t)N_NODES * HIDF * 2;   // 6.4 MB
    unsigned short* wt0 = (unsigned short*)p; p += (size_t)64 * 256 * 2;
    unsigned short* wt1 = (unsigned short*)p; p += (size_t)256 * 256 * 2;
    unsigned short* wt2 = (unsigned short*)p; p += (size_t)256 * 256 * 2;
    unsigned short* w1t = (unsigned short*)p; p += (size_t)64 * 128 * 2;
    unsigned short* w2t = (unsigned short*)p; p += (size_t)64 * 64 * 2;
    unsigned short* p0  = (unsigned short*)p; p += (size_t)64 * 8 * 2 + 16;
    float* alS  = (float*)p; p += (size_t)N_NODES * 4 * 4;
    float* alD  = (float*)p; p += (size_t)N_NODES * 4 * 4;
    float* part = (float*)p; p += (size_t)POOL_BLOCKS * GROUPS * D_F * 4;
    int* pcnt   = (int*)p;   p += (size_t)POOL_BLOCKS * GROUPS * 4;
    float* gsum = (float*)p; p += GROUPS * D_F * 4;
    int* gcnt   = (int*)p;   p += 16 * 4;
    int* deg    = (int*)p;   p += (size_t)N_NODES * 4;
    int* excl   = (int*)p;   p += (size_t)N_NODES * 4;
    int* bsums  = (int*)p;   p += 256 * 4;
    int* boff   = (int*)p;   p += 256 * 4;
    int* rowp   = (int*)p;   p += (size_t)(N_NODES + 4) * 4;
    int* cursor = (int*)p;   p += (size_t)N_NODES * 4;
    int* colx   = (int*)p;   p += (size_t)(E_EDGES + N_NODES) * 4;
    int* flag   = (int*)p;   p += 16;

    const int* srcI = ei;
    const int* dstI = ei + E_EDGES;

    SP sp;
    sp.q[0] = d_in[0];
    for (int t = 1; t < 25; ++t) sp.q[t] = d_in[t + 2];

    int nwb = (N_NODES + 3) / 4;
    int nb128 = (N_NODES + 127) / 128;

    flag_k<<<1, 64, 0, stream>>>((const unsigned short*)d_in[5], flag);
    convert_k<<<(CANON_TOT + 255) / 256, 256, 0, stream>>>(sp, flag, canon);
    wt_k<<<256, 256, 0, stream>>>(canon, wt0, wt1, wt2, w1t, w2t, p0);

    enc1_k<<<nb128, 128, 0, stream>>>(canon, w1t, bufB);
    enc2_k<<<nb128, 128, 0, stream>>>(canon, bufB, w2t, bufA);   // bufA = h0

    deg_init_k<<<NB256, 256, 0, stream>>>(deg);
    deg_count_k<<<(E_EDGES + 255) / 256, 256, 0, stream>>>(dstI, deg);
    scan1_k<<<NB256, 256, 0, stream>>>(deg, excl, bsums);
    scan2_k<<<1, 256, 0, stream>>>(bsums, boff, rowp + N_NODES);
    scan3_k<<<NB256, 256, 0, stream>>>(excl, boff, rowp, cursor);
    fill_k<<<(E_EDGES + N_NODES + 255) / 256, 256, 0, stream>>>(srcI, dstI, cursor, colx);

    dim3 mmg(2, nb128);
    // layer 0 (swapped): logits from h0 via P0; aggregate in 64-dim; then matmul w/ bias+ELU
    att0_k<<<(N_NODES * 8 + 255) / 256, 256, 0, stream>>>(bufA, p0, alS, alD);
    agg0_k<<<nwb, 256, 0, stream>>>(bufA, rowp, colx, alS, alD, zbuf);
    mfma_mm_k<<<mmg, 256, 0, stream>>>(zbuf, wt0, bufB, N_NODES, HIDF,
                                       canon + OFF_C0B, nullptr, nullptr, nullptr, nullptr);
    // layer 1
    mfma_mm_k<<<mmg, 256, 0, stream>>>(bufB, wt1, bufA, N_NODES, D_F,
                                       nullptr, canon + OFF_C1AS, canon + OFF_C1AD, alS, alD);
    agg_k<<<nwb, 256, 0, stream>>>(bufA, rowp, colx, alS, alD, canon + OFF_C1B, bufB);
    // layer 2
    mfma_mm_k<<<mmg, 256, 0, stream>>>(bufB, wt2, bufA, N_NODES, D_F,
                                       nullptr, canon + OFF_C2AS, canon + OFF_C2AD, alS, alD);
    agg_k<<<nwb, 256, 0, stream>>>(bufA, rowp, colx, alS, alD, canon + OFF_C2B, bufB);

    pool_k<<<POOL_BLOCKS, 256, 0, stream>>>(bufB, batch, part, pcnt);
    reduce_k<<<GROUPS, 256, 0, stream>>>(part, pcnt, gsum, gcnt);
    dec_k<<<2, 256, 0, stream>>>(gsum, gcnt, canon, flag, d_out);
}